// Round 4
// baseline (162.692 us; speedup 1.0000x reference)
//
#include <hip/hip_runtime.h>

typedef unsigned short u16;
typedef unsigned int u32;

#define B_ 2
#define L_ 4096
#define D_ 512
#define H_ 8
#define E_ 64
#define M_ (B_*L_)        // 8192 rows
#define TD (3*D_)         // 1536
#define NCH (L_/64)       // 64 chunks of 64 per sequence
#define BH (B_*H_)        // 16

typedef short bf16x8 __attribute__((ext_vector_type(8)));
typedef float f32x4 __attribute__((ext_vector_type(4)));

__device__ __forceinline__ float bf2f(u16 u){ return __uint_as_float(((u32)u)<<16); }
__device__ __forceinline__ u16 f2bf(float f){
  u32 u = __float_as_uint(f);
  u32 r = u + 0x7FFFu + ((u>>16)&1u);   // RNE; inputs finite
  return (u16)(r>>16);
}
__device__ __forceinline__ float elu1(float v){ return v>0.f ? v+1.f : __expf(v); }

__device__ __forceinline__ void async_ld16(const u16* g, u16* l){
  __builtin_amdgcn_global_load_lds(
      (const __attribute__((address_space(1))) void*)g,
      (__attribute__((address_space(3))) void*)l, 16, 0, 0);
}

// ---------------- K1: decay logits + x->bf16 + weight conversions ----------------
__global__ __launch_bounds__(256) void decay_conv_kernel(const float* __restrict__ x,
    const float* __restrict__ dw, const float* __restrict__ db,
    const float* __restrict__ qw, const float* __restrict__ ow,
    float* __restrict__ ll, u16* __restrict__ xb,
    u16* __restrict__ qwb, u16* __restrict__ owb)
{
  int blk = blockIdx.x;
  if (blk < 2048){
    int wv = threadIdx.x>>6, lane = threadIdx.x&63;
    int m = blk*4 + wv;
    float xr[8];
    #pragma unroll
    for (int i=0;i<8;i++) xr[i] = x[(size_t)m*D_ + lane + 64*i];
    #pragma unroll
    for (int i=0;i<8;i++) xb[(size_t)m*D_ + lane + 64*i] = f2bf(xr[i]);
    int b = m >> 12, l = m & (L_-1);
    float acc8[8];
    #pragma unroll
    for (int h=0; h<8; h++){
      float a = 0.f;
      #pragma unroll
      for (int i=0;i<8;i++) a += xr[i]*dw[h*D_ + lane + 64*i];
      acc8[h] = a;
    }
    float s4[4];
    #pragma unroll
    for (int i=0;i<4;i++){
      float a = acc8[2*i], bb = acc8[2*i+1];
      bool odd = lane & 1;
      float keep = odd ? bb : a;
      float send = odd ? a : bb;
      s4[i] = keep + __shfl_xor(send, 1);
    }
    float s2[2];
    #pragma unroll
    for (int j=0;j<2;j++){
      float a = s4[2*j], bb = s4[2*j+1];
      bool sel = (lane>>1) & 1;
      float keep = sel ? bb : a;
      float send = sel ? a : bb;
      s2[j] = keep + __shfl_xor(send, 2);
    }
    float r;
    {
      bool sel = (lane>>2) & 1;
      float keep = sel ? s2[1] : s2[0];
      float send = sel ? s2[0] : s2[1];
      r = keep + __shfl_xor(send, 4);
    }
    r += __shfl_xor(r, 8);
    r += __shfl_xor(r, 16);
    r += __shfl_xor(r, 32);
    if (lane < 8){
      float z = r + db[lane];
      float lam = 0.9f + 0.1f/(1.f + __expf(-z));
      ll[((b*H_+lane)*L_) + l] = __logf(lam);
    }
  } else {
    int gid = (blk-2048)*256 + threadIdx.x;   // 262144 float4 groups
    const float* src; u16* dst; int off;
    if (gid < 196608){ src = qw; dst = qwb; off = gid; }
    else { src = ow; dst = owb; off = gid - 196608; }
    float4 v = ((const float4*)src)[off];
    ushort4 o; o.x=f2bf(v.x); o.y=f2bf(v.y); o.z=f2bf(v.z); o.w=f2bf(v.w);
    ((ushort4*)dst)[off] = o;
  }
}

// ---------------- K2: inclusive scan over L (shfl-based), clip to [-50,50] ----------------
__global__ __launch_bounds__(256) void scan_kernel(const float* __restrict__ ll,
    float* __restrict__ cb)
{
  int bh = blockIdx.x, t = threadIdx.x;
  int lane = t & 63, wv = t >> 6;
  const float* p = ll + (size_t)bh*L_ + t*16;
  float s[16];
  #pragma unroll
  for (int q=0;q<4;q++){
    float4 v = *(const float4*)(p + q*4);
    s[q*4+0]=v.x; s[q*4+1]=v.y; s[q*4+2]=v.z; s[q*4+3]=v.w;
  }
  #pragma unroll
  for (int i=1;i<16;i++) s[i] += s[i-1];
  float tot = s[15];
  float ws = tot;
  #pragma unroll
  for (int off=1; off<64; off<<=1){
    float tmp = __shfl_up(ws, off);
    if (lane >= off) ws += tmp;
  }
  __shared__ float wsum[4];
  if (lane == 63) wsum[wv] = ws;
  __syncthreads();
  float base = 0.f;
  #pragma unroll
  for (int w2=0; w2<3; w2++) if (w2 < wv) base += wsum[w2];
  float ex = base + ws - tot;
  float* c = cb + (size_t)bh*L_ + t*16;
  #pragma unroll
  for (int i=0;i<16;i++) c[i] = fminf(50.f, fmaxf(-50.f, ex + s[i]));
}

// ---------------- K3: QKV GEMM with fused transform epilogue ----------------
// Writes q~ (elu+1, *exp(c)/8) and k~ (elu+1, *exp(-c)) and raw v DIRECTLY in the
// chunked layout [bid][e-half][l][32]. Eliminates the qkvb intermediate entirely.
__global__ __launch_bounds__(256) void gemm_qkv_fused(const u16* __restrict__ A,
    const u16* __restrict__ W, const float* __restrict__ bias,
    const float* __restrict__ cb,
    u16* __restrict__ qc, u16* __restrict__ kc, u16* __restrict__ vc)
{
  __shared__ u16 As[2][128*32];
  __shared__ u16 Bs[2][128*32];
  const int K = 512;
  int n0 = blockIdx.x*128, m0 = blockIdx.y*128;
  int t = threadIdx.x, wave = t>>6, lane = t&63;
  int wm = (wave>>1)*64, wn = (wave&1)*64;
  f32x4 acc[4][4] = {};
  int srow = wave*32 + (lane>>2);
  int scol = (lane&3)*8;
  const u16* gA = A + (size_t)(m0+srow)*K + scol;
  const u16* gB = W + (size_t)(n0+srow)*K + scol;
  int q8 = (lane>>4)*8, r16 = lane&15;
  {
    u16* lA = As[0] + wave*1024;
    u16* lB = Bs[0] + wave*1024;
    async_ld16(gA,                lA);
    async_ld16(gA + 16*(size_t)K, lA + 512);
    async_ld16(gB,                lB);
    async_ld16(gB + 16*(size_t)K, lB + 512);
  }
  __syncthreads();
  int cur = 0;
  #pragma unroll 2
  for (int k0=0; k0<K; k0+=32){
    if (k0 + 32 < K){
      u16* lA = As[cur^1] + wave*1024;
      u16* lB = Bs[cur^1] + wave*1024;
      async_ld16(gA + k0+32,                lA);
      async_ld16(gA + k0+32 + 16*(size_t)K, lA + 512);
      async_ld16(gB + k0+32,                lB);
      async_ld16(gB + k0+32 + 16*(size_t)K, lB + 512);
    }
    bf16x8 af[4], bfr[4];
    #pragma unroll
    for (int i=0;i<4;i++) af[i]  = *(const bf16x8*)&As[cur][(wm + i*16 + r16)*32 + q8];
    #pragma unroll
    for (int j=0;j<4;j++) bfr[j] = *(const bf16x8*)&Bs[cur][(wn + j*16 + r16)*32 + q8];
    #pragma unroll
    for (int i=0;i<4;i++)
      #pragma unroll
      for (int j=0;j<4;j++)
        acc[i][j] = __builtin_amdgcn_mfma_f32_16x16x32_bf16(af[i], bfr[j], acc[i][j], 0,0,0);
    __syncthreads();
    cur ^= 1;
  }
  // fused epilogue: bias + (q/k transform) + chunked store
  int g = lane>>4;
  int sec = n0 >> 9;                          // 0=q, 1=k, 2=v (uniform per block)
  #pragma unroll
  for (int i=0;i<4;i++){
    int rowb = m0 + wm + i*16 + g*4;
    #pragma unroll
    for (int j=0;j<4;j++){
      int col = n0 + wn + j*16 + r16;
      float bv = bias[col];
      int nn = col & 511, h2 = nn>>6, e = nn&63;
      int bh2 = ((rowb>>12)<<3) | h2;         // rowb%4==0 -> rowb>>12 == row>>12
      #pragma unroll
      for (int r=0;r<4;r++){
        int row = rowb + r;
        float val = acc[i][j][r] + bv;
        int l6 = row & 63, ch = (row>>6)&63;
        int bid = (bh2<<6) | ch;
        size_t a = ((size_t)(bid*2 + (e>>5)))*2048 + (size_t)l6*32 + (e&31);
        if (sec == 0){
          float c = cb[((size_t)bh2<<12) | (row & 4095)];
          qc[a] = f2bf(elu1(val)*__expf(c)*0.125f);
        } else if (sec == 1){
          float c = cb[((size_t)bh2<<12) | (row & 4095)];
          kc[a] = f2bf(elu1(val)*__expf(-c));
        } else {
          vc[a] = f2bf(val);
        }
      }
    }
  }
}

// ---------------- K4: per-chunk S^T MFMA + k~ sums (from chunked k~/v) ----------------
__global__ __launch_bounds__(256) void chunk_sums_kernel(const u16* __restrict__ kc,
    const u16* __restrict__ vc, u16* __restrict__ Stc, float* __restrict__ ksc)
{
  int bid = blockIdx.x;
  __shared__ u16 Kc[4096], Vc[4096];
  __shared__ u16 Ktl[5120], Vtl[5120];     // [2][64][40] padded
  __shared__ float ksr[256];
  int t = threadIdx.x, w = t>>6, lane = t&63;
  {
    const u16* gk = kc + (size_t)bid*4096 + w*1024 + lane*8;
    const u16* gv = vc + (size_t)bid*4096 + w*1024 + lane*8;
    async_ld16(gk,       Kc + w*1024);
    async_ld16(gk + 512, Kc + w*1024 + 512);
    async_ld16(gv,       Vc + w*1024);
    async_ld16(gv + 512, Vc + w*1024 + 512);
  }
  __syncthreads();
  int e = t & 63, jq = t >> 6;
  {
    u16 kv[16] __attribute__((aligned(16)));
    u16 vv[16] __attribute__((aligned(16)));
    float ksum = 0.f;
    #pragma unroll
    for (int jj=0;jj<16;jj++){
      int j = jq*16+jj;
      kv[jj] = Kc[(e>>5)*2048 + j*32 + (e&31)];
      ksum += bf2f(kv[jj]);
      vv[jj] = Vc[(e>>5)*2048 + j*32 + (e&31)];
    }
    int kh2 = jq>>1, jl = (jq&1)*16;
    u16* kt = &Ktl[(kh2*64 + e)*40 + jl];
    u16* vt = &Vtl[(kh2*64 + e)*40 + jl];
    *(uint4*)kt     = *(const uint4*)&kv[0];
    *(uint4*)(kt+8) = *(const uint4*)&kv[8];
    *(uint4*)vt     = *(const uint4*)&vv[0];
    *(uint4*)(vt+8) = *(const uint4*)&vv[8];
    ksr[t] = ksum;
  }
  __syncthreads();
  int r16 = lane & 15, q8 = (lane>>4)*8;
  bf16x8 av[2];
  #pragma unroll
  for (int kh=0;kh<2;kh++)
    av[kh] = *(const bf16x8*)&Vtl[(kh*64 + w*16 + r16)*40 + q8];
  f32x4 acc[4] = {};
  #pragma unroll
  for (int et=0;et<4;et++)
    #pragma unroll
    for (int kh=0;kh<2;kh++){
      bf16x8 bv = *(const bf16x8*)&Ktl[(kh*64 + et*16 + r16)*40 + q8];
      acc[et] = __builtin_amdgcn_mfma_f32_16x16x32_bf16(av[kh], bv, acc[et], 0,0,0);
    }
  #pragma unroll
  for (int et=0;et<4;et++){
    int eh = et>>1, el = (et&1)*16 + r16;
    #pragma unroll
    for (int r=0;r<4;r++){
      int f = w*16 + (lane>>4)*4 + r;
      Stc[((size_t)bid*2 + eh)*2048 + f*32 + el] = f2bf(acc[et][r]);
    }
  }
  if (t < 64) ksc[bid*64 + t] = ksr[t] + ksr[64+t] + ksr[128+t] + ksr[192+t];
}

// ---------------- K5: exclusive prefix over chunks ----------------
__global__ __launch_bounds__(256) void chunk_prefix_kernel(u16* __restrict__ Stc,
    float* __restrict__ ksc)
{
  int blk = blockIdx.x, t = threadIdx.x;
  if (blk < 128){
    int gid = blk*256 + t;                 // 32768 threads
    int bh = gid >> 11, e2 = gid & 2047;
    u32* p = (u32*)Stc + (size_t)bh*131072 + e2;
    float r0 = 0.f, r1 = 0.f;
    #pragma unroll 16
    for (int ch=0; ch<NCH; ch++){
      u32 v = p[ch*2048];
      float lo = bf2f((u16)(v & 0xffffu));
      float hi = bf2f((u16)(v >> 16));
      p[ch*2048] = (u32)f2bf(r0) | ((u32)f2bf(r1) << 16);
      r0 += lo; r1 += hi;
    }
  } else {
    int gid2 = (blk-128)*256 + t;          // 1024 threads = BH*64
    int bh2 = gid2 >> 6, e = gid2 & 63;
    float* kp = ksc + bh2*4096 + e;
    float kr = 0.f;
    #pragma unroll 8
    for (int ch=0; ch<NCH; ch++){
      float v = kp[ch*64]; kp[ch*64] = kr; kr += v;
    }
  }
}

// ---------------- K6: chunk output (Q fragments direct-from-global; V transposed in LDS) ----------------
__global__ __launch_bounds__(256) void chunk_out_kernel(const u16* __restrict__ qc,
    const u16* __restrict__ kc, const u16* __restrict__ vc,
    const u16* __restrict__ Stc, const float* __restrict__ ksc,
    u16* __restrict__ attn)
{
  int bid = blockIdx.x;
  int bh = bid >> 6, ch = bid & 63;
  int b = bh >> 3, h = bh & 7;
  __shared__ u16 Kb_l[4096];
  __shared__ u16 Vc_l[4096];
  __shared__ u16 St_l[4096];
  __shared__ u16 Vt[5120];       // [2][64][40] padded
  __shared__ u16 Ab[4096];       // [jh][l][32]
  __shared__ float R2[320];      // [0..255] den4, [256..319] den
  int t = threadIdx.x, w = t>>6, lane = t&63;
  size_t mbase = (size_t)b*L_ + ch*64;
  {
    const u16* gk = kc  + (size_t)bid*4096 + w*1024 + lane*8;
    const u16* gv = vc  + (size_t)bid*4096 + w*1024 + lane*8;
    const u16* gs = Stc + (size_t)bid*4096 + w*1024 + lane*8;
    async_ld16(gk,       Kb_l + w*1024);
    async_ld16(gk + 512, Kb_l + w*1024 + 512);
    async_ld16(gv,       Vc_l + w*1024);
    async_ld16(gv + 512, Vc_l + w*1024 + 512);
    async_ld16(gs,       St_l + w*1024);
    async_ld16(gs + 512, St_l + w*1024 + 512);
  }
  int r16 = lane & 15, q8 = (lane>>4)*8;
  // Q fragments + kp: issued before the barrier so latency hides under staging
  const u16* qg = qc + (size_t)bid*4096;
  bf16x8 aq[2];
  #pragma unroll
  for (int eh=0;eh<2;eh++)
    aq[eh] = *(const bf16x8*)(qg + eh*2048 + (w*16 + r16)*32 + q8);
  int l4 = t>>2, q4 = t&3;
  int ehd = q4>>1, el0 = (q4&1)*16;
  bf16x8 x1 = *(const bf16x8*)(qg + ehd*2048 + l4*32 + el0);
  bf16x8 x2 = *(const bf16x8*)(qg + ehd*2048 + l4*32 + el0 + 8);
  union { float4 v[4]; float f[16]; } kp;
  #pragma unroll
  for (int qq=0;qq<4;qq++)
    kp.v[qq] = *(const float4*)(ksc + bid*64 + q4*16 + qq*4);
  __syncthreads();   // B1: staging drained
  // V transpose: Vc_l (chunk row layout) -> Vt (padded 40)
  {
    int e = t & 63, jq = t >> 6;
    u16 vv[16] __attribute__((aligned(16)));
    #pragma unroll
    for (int jj=0;jj<16;jj++)
      vv[jj] = Vc_l[(e>>5)*2048 + (jq*16+jj)*32 + (e&31)];
    int jh = jq>>1, jl = (jq&1)*16;
    u16* vt = &Vt[(jh*64 + e)*40 + jl];
    *(uint4*)vt     = *(const uint4*)&vv[0];
    *(uint4*)(vt+8) = *(const uint4*)&vv[8];
  }
  // matmul1: A = Q~ K~^T  (strip l = w*16..w*16+15)
  f32x4 accA[4] = {};
  #pragma unroll
  for (int jt=0;jt<4;jt++)
    #pragma unroll
    for (int eh=0;eh<2;eh++){
      bf16x8 bv = *(const bf16x8*)&Kb_l[(eh*64 + jt*16 + r16)*32 + q8];
      accA[jt] = __builtin_amdgcn_mfma_f32_16x16x32_bf16(aq[eh], bv, accA[jt], 0,0,0);
    }
  // den: q~ . kp part
  float dkp = 0.f;
  #pragma unroll
  for (int i=0;i<8;i++)
    dkp += bf2f((u16)x1[i])*kp.f[i] + bf2f((u16)x2[i])*kp.f[8+i];
  // mask + write A to LDS (bf16, split layout)
  #pragma unroll
  for (int jt=0;jt<4;jt++)
    #pragma unroll
    for (int r=0;r<4;r++){
      int lr = w*16 + ((lane>>4)<<2) + r;
      int j  = jt*16 + r16;
      Ab[((jt>>1)*64 + lr)*32 + (jt&1)*16 + r16] = (j <= lr) ? f2bf(accA[jt][r]) : (u16)0;
    }
  __syncthreads();   // B2: Ab + Vt visible
  // den: masked row-sum of A
  float dA = 0.f;
  {
    int jh2 = q4>>1, jl0 = (q4&1)*16;
    bf16x8 y1 = *(const bf16x8*)&Ab[(jh2*64 + l4)*32 + jl0];
    bf16x8 y2 = *(const bf16x8*)&Ab[(jh2*64 + l4)*32 + jl0 + 8];
    #pragma unroll
    for (int i=0;i<8;i++) dA += bf2f((u16)y1[i]) + bf2f((u16)y2[i]);
  }
  R2[t] = dkp + dA;
  __syncthreads();   // B3
  if (t < 64) R2[256+t] = R2[t*4] + R2[t*4+1] + R2[t*4+2] + R2[t*4+3] + 1e-6f;
  // matmul2: num = A V + Q~ S^T
  bf16x8 aA[2];
  #pragma unroll
  for (int jh=0;jh<2;jh++)
    aA[jh] = *(const bf16x8*)&Ab[(jh*64 + w*16 + r16)*32 + q8];
  f32x4 acc[4] = {};
  #pragma unroll
  for (int ft=0;ft<4;ft++){
    #pragma unroll
    for (int jh=0;jh<2;jh++){
      bf16x8 bv = *(const bf16x8*)&Vt[(jh*64 + ft*16 + r16)*40 + q8];
      acc[ft] = __builtin_amdgcn_mfma_f32_16x16x32_bf16(aA[jh], bv, acc[ft], 0,0,0);
    }
    #pragma unroll
    for (int eh=0;eh<2;eh++){
      bf16x8 bv = *(const bf16x8*)&St_l[(eh*64 + ft*16 + r16)*32 + q8];
      acc[ft] = __builtin_amdgcn_mfma_f32_16x16x32_bf16(aq[eh], bv, acc[ft], 0,0,0);
    }
  }
  __syncthreads();   // B4: den ready
  float inv[4];
  #pragma unroll
  for (int r=0;r<4;r++) inv[r] = 1.f / R2[256 + w*16 + ((lane>>4)<<2) + r];
  #pragma unroll
  for (int ft=0;ft<4;ft++)
    #pragma unroll
    for (int r=0;r<4;r++){
      int lr = w*16 + ((lane>>4)<<2) + r;
      attn[(mbase + lr)*D_ + h*64 + ft*16 + r16] = f2bf(acc[ft][r]*inv[r]);
    }
}

// ---------------- K7: out-projection GEMM fused with RMSNorm epilogue ----------------
__global__ __launch_bounds__(256) void gemm_rms_kernel(const u16* __restrict__ A,
    const u16* __restrict__ W, const float* __restrict__ bias,
    const float* __restrict__ gnorm, float* __restrict__ out)
{
  __shared__ u16 As[2][32*32];
  __shared__ u16 Bs[2][512*32];
  __shared__ float ssq_l[4][32];
  __shared__ float rinv_l[32];
  int m0 = blockIdx.x*32;
  int t = threadIdx.x, wave = t>>6, lane = t&63;
  int wn = wave*128;
  int r16 = lane&15, q8 = (lane>>4)*8;
  f32x4 acc[2][8] = {};
  int scol = (t&3)*8;
  const u16* gB = W + (size_t)(t>>2)*512 + scol;
  const u16* gA = A + (size_t)(m0 + (t>>2))*512 + scol;
  {
    if (wave < 2) async_ld16(gA, As[0] + wave*512);
    #pragma unroll
    for (int it=0; it<8; it++)
      async_ld16(gB + it*32768, Bs[0] + wave*512 + it*2048);
  }
  __syncthreads();
  int cur = 0;
  #pragma unroll 2
  for (int k0=0; k0<512; k0+=32){
    if (k0 < 480){
      if (wave < 2) async_ld16(gA + k0+32, As[cur^1] + wave*512);
      #pragma unroll
      for (int it=0; it<8; it++)
        async_ld16(gB + k0+32 + it*32768, Bs[cur^1] + wave*512 + it*2048);
    }
    bf16x8 af0 = *(const bf16x8*)&As[cur][r16*32 + q8];
    bf16x8 af1 = *(const bf16x8*)&As[cur][(16 + r16)*32 + q8];
    #pragma unroll
    for (int j=0;j<8;j++){
      bf16x8 bv = *(const bf16x8*)&Bs[cur][(wn + j*16 + r16)*32 + q8];
      acc[0][j] = __builtin_amdgcn_mfma_f32_16x16x32_bf16(af0, bv, acc[0][j], 0,0,0);
      acc[1][j] = __builtin_amdgcn_mfma_f32_16x16x32_bf16(af1, bv, acc[1][j], 0,0,0);
    }
    __syncthreads();
    cur ^= 1;
  }
  int g = lane>>4;
  float bv8[8], gv8[8];
  #pragma unroll
  for (int j=0;j<8;j++){ int col = wn + j*16 + r16; bv8[j] = bias[col]; gv8[j] = gnorm[col]; }
  float ssq[2][4] = {};
  #pragma unroll
  for (int i=0;i<2;i++)
    #pragma unroll
    for (int j=0;j<8;j++)
      #pragma unroll
      for (int r=0;r<4;r++){
        float v = acc[i][j][r] + bv8[j];
        acc[i][j][r] = v;
        ssq[i][r] += v*v;
      }
  #pragma unroll
  for (int off=1; off<16; off<<=1)
    #pragma unroll
    for (int i=0;i<2;i++)
      #pragma unroll
      for (int r=0;r<4;r++)
        ssq[i][r] += __shfl_xor(ssq[i][r], off);
  if (r16 == 0){
    #pragma unroll
    for (int i=0;i<2;i++)
      #pragma unroll
      for (int r=0;r<4;r++)
        ssq_l[wave][i*16 + g*4 + r] = ssq[i][r];
  }
  __syncthreads();
  if (t < 32)
    rinv_l[t] = rsqrtf((ssq_l[0][t]+ssq_l[1][t]+ssq_l[2][t]+ssq_l[3][t])*(1.f/512.f) + 1e-8f);
  __syncthreads();
  #pragma unroll
  for (int i=0;i<2;i++)
    #pragma unroll
    for (int r=0;r<4;r++){
      int row = m0 + i*16 + g*4 + r;
      float ri = rinv_l[i*16 + g*4 + r];
      #pragma unroll
      for (int j=0;j<8;j++)
        out[(size_t)row*512 + wn + j*16 + r16] = acc[i][j][r]*ri*gv8[j];
    }
}

extern "C" void kernel_launch(void* const* d_in, const int* in_sizes, int n_in,
                              void* d_out, int out_size, void* d_ws, size_t ws_size,
                              hipStream_t stream)
{
  const float* x     = (const float*)d_in[0];
  const float* w_qkv = (const float*)d_in[1];
  const float* b_qkv = (const float*)d_in[2];
  const float* w_out = (const float*)d_in[3];
  const float* b_out = (const float*)d_in[4];
  const float* w_dec = (const float*)d_in[5];
  const float* b_dec = (const float*)d_in[6];
  const float* gnorm = (const float*)d_in[7];
  float* out = (float*)d_out;

  char* ws = (char*)d_ws;
  u16*   qc   = (u16*)(ws);                    //  8,388,608  chunked q~
  u16*   kc   = (u16*)(ws + 8388608);          //  8,388,608  chunked k~
  u16*   vc   = (u16*)(ws + 16777216);         //  8,388,608  chunked raw v
  u16*   Stc  = (u16*)(ws + 25165824);         //  8,388,608  chunked [bid][eh][f][32]
  float* ksc  = (float*)(ws + 33554432);       //    262,144
  float* ll   = (float*)(ws + 33816576);       //    262,144
  float* cb   = (float*)(ws + 34078720);       //    262,144
  u16*   xb   = (u16*)(ws + 34340864);         //  8,388,608  (attn reuses)
  u16*   qwb  = (u16*)(ws + 42729472);         //  1,572,864
  u16*   owb  = (u16*)(ws + 44302336);         //    524,288  total 44,826,624
  u16*   attn = xb;

  decay_conv_kernel<<<dim3(3072), dim3(256), 0, stream>>>(x, w_dec, b_dec, w_qkv, w_out,
                                                          ll, xb, qwb, owb);
  scan_kernel<<<dim3(BH), dim3(256), 0, stream>>>(ll, cb);
  gemm_qkv_fused<<<dim3(TD/128, M_/128), dim3(256), 0, stream>>>(xb, qwb, b_qkv, cb, qc, kc, vc);
  chunk_sums_kernel<<<dim3(BH*NCH), dim3(256), 0, stream>>>(kc, vc, Stc, ksc);
  chunk_prefix_kernel<<<dim3(132), dim3(256), 0, stream>>>(Stc, ksc);
  chunk_out_kernel<<<dim3(BH*NCH), dim3(256), 0, stream>>>(qc, kc, vc, Stc, ksc, attn);
  gemm_rms_kernel<<<dim3(M_/32), dim3(256), 0, stream>>>(attn, owb, b_out, gnorm, out);
}

// Round 5
// 154.405 us; speedup vs baseline: 1.0537x; 1.0537x over previous
//
#include <hip/hip_runtime.h>

typedef unsigned short u16;
typedef unsigned int u32;

#define B_ 2
#define L_ 4096
#define D_ 512
#define H_ 8
#define E_ 64
#define M_ (B_*L_)        // 8192 rows
#define TD (3*D_)         // 1536
#define NCH (L_/64)       // 64 chunks of 64 per sequence
#define BH (B_*H_)        // 16

typedef short bf16x8 __attribute__((ext_vector_type(8)));
typedef float f32x4 __attribute__((ext_vector_type(4)));

__device__ __forceinline__ float bf2f(u16 u){ return __uint_as_float(((u32)u)<<16); }
__device__ __forceinline__ u16 f2bf(float f){
  u32 u = __float_as_uint(f);
  u32 r = u + 0x7FFFu + ((u>>16)&1u);   // RNE; inputs finite
  return (u16)(r>>16);
}
__device__ __forceinline__ float elu1(float v){ return v>0.f ? v+1.f : __expf(v); }

__device__ __forceinline__ void async_ld16(const u16* g, u16* l){
  __builtin_amdgcn_global_load_lds(
      (const __attribute__((address_space(1))) void*)g,
      (__attribute__((address_space(3))) void*)l, 16, 0, 0);
}

// ---------------- K1: decay logits + x->bf16 + weight conversions ----------------
__global__ __launch_bounds__(256) void decay_conv_kernel(const float* __restrict__ x,
    const float* __restrict__ dw, const float* __restrict__ db,
    const float* __restrict__ qw, const float* __restrict__ ow,
    float* __restrict__ ll, u16* __restrict__ xb,
    u16* __restrict__ qwb, u16* __restrict__ owb)
{
  int blk = blockIdx.x;
  if (blk < 2048){
    int wv = threadIdx.x>>6, lane = threadIdx.x&63;
    int m = blk*4 + wv;
    float xr[8];
    #pragma unroll
    for (int i=0;i<8;i++) xr[i] = x[(size_t)m*D_ + lane + 64*i];
    #pragma unroll
    for (int i=0;i<8;i++) xb[(size_t)m*D_ + lane + 64*i] = f2bf(xr[i]);
    int b = m >> 12, l = m & (L_-1);
    float acc8[8];
    #pragma unroll
    for (int h=0; h<8; h++){
      float a = 0.f;
      #pragma unroll
      for (int i=0;i<8;i++) a += xr[i]*dw[h*D_ + lane + 64*i];
      acc8[h] = a;
    }
    float s4[4];
    #pragma unroll
    for (int i=0;i<4;i++){
      float a = acc8[2*i], bb = acc8[2*i+1];
      bool odd = lane & 1;
      float keep = odd ? bb : a;
      float send = odd ? a : bb;
      s4[i] = keep + __shfl_xor(send, 1);
    }
    float s2[2];
    #pragma unroll
    for (int j=0;j<2;j++){
      float a = s4[2*j], bb = s4[2*j+1];
      bool sel = (lane>>1) & 1;
      float keep = sel ? bb : a;
      float send = sel ? a : bb;
      s2[j] = keep + __shfl_xor(send, 2);
    }
    float r;
    {
      bool sel = (lane>>2) & 1;
      float keep = sel ? s2[1] : s2[0];
      float send = sel ? s2[0] : s2[1];
      r = keep + __shfl_xor(send, 4);
    }
    r += __shfl_xor(r, 8);
    r += __shfl_xor(r, 16);
    r += __shfl_xor(r, 32);
    if (lane < 8){
      float z = r + db[lane];
      float lam = 0.9f + 0.1f/(1.f + __expf(-z));
      ll[((b*H_+lane)*L_) + l] = __logf(lam);
    }
  } else {
    int gid = (blk-2048)*256 + threadIdx.x;   // 262144 float4 groups
    const float* src; u16* dst; int off;
    if (gid < 196608){ src = qw; dst = qwb; off = gid; }
    else { src = ow; dst = owb; off = gid - 196608; }
    float4 v = ((const float4*)src)[off];
    ushort4 o; o.x=f2bf(v.x); o.y=f2bf(v.y); o.z=f2bf(v.z); o.w=f2bf(v.w);
    ((ushort4*)dst)[off] = o;
  }
}

// ---------------- K2: inclusive scan over L (shfl-based), clip to [-50,50] ----------------
__global__ __launch_bounds__(256) void scan_kernel(const float* __restrict__ ll,
    float* __restrict__ cb)
{
  int bh = blockIdx.x, t = threadIdx.x;
  int lane = t & 63, wv = t >> 6;
  const float* p = ll + (size_t)bh*L_ + t*16;
  float s[16];
  #pragma unroll
  for (int q=0;q<4;q++){
    float4 v = *(const float4*)(p + q*4);
    s[q*4+0]=v.x; s[q*4+1]=v.y; s[q*4+2]=v.z; s[q*4+3]=v.w;
  }
  #pragma unroll
  for (int i=1;i<16;i++) s[i] += s[i-1];
  float tot = s[15];
  float ws = tot;
  #pragma unroll
  for (int off=1; off<64; off<<=1){
    float tmp = __shfl_up(ws, off);
    if (lane >= off) ws += tmp;
  }
  __shared__ float wsum[4];
  if (lane == 63) wsum[wv] = ws;
  __syncthreads();
  float base = 0.f;
  #pragma unroll
  for (int w2=0; w2<3; w2++) if (w2 < wv) base += wsum[w2];
  float ex = base + ws - tot;
  float* c = cb + (size_t)bh*L_ + t*16;
  #pragma unroll
  for (int i=0;i<16;i++) c[i] = fminf(50.f, fmaxf(-50.f, ex + s[i]));
}

// ---------------- K3: QKV GEMM with fused transform epilogue (LDS-staged) ----------------
// Main loop unchanged. Epilogue v2: acc+bias -> bf16 LDS tile Ct[128][136], barrier,
// then 8 x uint4 chunked stores per thread with ONE cb-load/expf/addr-calc per 8 elems.
// Numerics identical to the R2 split path (bf16 rounding before elu1).
__global__ __launch_bounds__(256) void gemm_qkv_fused(const u16* __restrict__ A,
    const u16* __restrict__ W, const float* __restrict__ bias,
    const float* __restrict__ cb,
    u16* __restrict__ qc, u16* __restrict__ kc, u16* __restrict__ vc)
{
  __shared__ u16 SM[17408];            // 34816 B; K-loop: As|Bs (32 KB); epilogue: Ct[128][136]
  u16* As0 = SM;                       // [2][4096]
  u16* Bs0 = SM + 8192;                // [2][4096]
  const int K = 512;
  int n0 = blockIdx.x*128, m0 = blockIdx.y*128;
  int t = threadIdx.x, wave = t>>6, lane = t&63;
  int wm = (wave>>1)*64, wn = (wave&1)*64;
  f32x4 acc[4][4] = {};
  int srow = wave*32 + (lane>>2);
  int scol = (lane&3)*8;
  const u16* gA = A + (size_t)(m0+srow)*K + scol;
  const u16* gB = W + (size_t)(n0+srow)*K + scol;
  int q8 = (lane>>4)*8, r16 = lane&15;
  {
    u16* lA = As0 + wave*1024;
    u16* lB = Bs0 + wave*1024;
    async_ld16(gA,                lA);
    async_ld16(gA + 16*(size_t)K, lA + 512);
    async_ld16(gB,                lB);
    async_ld16(gB + 16*(size_t)K, lB + 512);
  }
  __syncthreads();
  int cur = 0;
  #pragma unroll 2
  for (int k0=0; k0<K; k0+=32){
    if (k0 + 32 < K){
      u16* lA = As0 + (cur^1)*4096 + wave*1024;
      u16* lB = Bs0 + (cur^1)*4096 + wave*1024;
      async_ld16(gA + k0+32,                lA);
      async_ld16(gA + k0+32 + 16*(size_t)K, lA + 512);
      async_ld16(gB + k0+32,                lB);
      async_ld16(gB + k0+32 + 16*(size_t)K, lB + 512);
    }
    bf16x8 af[4], bfr[4];
    #pragma unroll
    for (int i=0;i<4;i++) af[i]  = *(const bf16x8*)&As0[cur*4096 + (wm + i*16 + r16)*32 + q8];
    #pragma unroll
    for (int j=0;j<4;j++) bfr[j] = *(const bf16x8*)&Bs0[cur*4096 + (wn + j*16 + r16)*32 + q8];
    #pragma unroll
    for (int i=0;i<4;i++)
      #pragma unroll
      for (int j=0;j<4;j++)
        acc[i][j] = __builtin_amdgcn_mfma_f32_16x16x32_bf16(af[i], bfr[j], acc[i][j], 0,0,0);
    __syncthreads();
    cur ^= 1;
  }
  // ---- epilogue v2 ----
  int g = lane>>4;
  // 1) acc+bias -> Ct[128][136] bf16
  #pragma unroll
  for (int j=0;j<4;j++){
    int col = wn + j*16 + r16;
    float bv = bias[n0 + col];
    #pragma unroll
    for (int i=0;i<4;i++){
      int rbase = wm + i*16 + g*4;
      #pragma unroll
      for (int r=0;r<4;r++)
        SM[(rbase+r)*136 + col] = f2bf(acc[i][j][r] + bv);
    }
  }
  __syncthreads();
  // 2) transform + chunked uint4 stores
  int sec = n0 >> 9;                   // 0=q, 1=k, 2=v (uniform per block)
  #pragma unroll
  for (int u=0;u<8;u++){
    int idx = t + 256*u;               // 2048 uint4 groups
    int rloc = idx >> 4;               // 0..127
    int colg = (idx & 15) * 8;         // 0..120
    int row = m0 + rloc;
    int nn = (n0 + colg) & 511;
    int h2 = nn>>6, e0 = nn&63;
    int bh2 = ((row>>12)<<3) | h2;
    int bid = (bh2<<6) | ((row>>6)&63);
    int l6 = row & 63;
    union { uint4 v; u16 s[8]; } dat;
    dat.v = *(const uint4*)&SM[rloc*136 + colg];
    size_t a = ((size_t)(bid*2 + (e0>>5)))*2048 + (size_t)l6*32 + (e0&31);
    if (sec == 0){
      float eqc = __expf(cb[((size_t)bh2<<12) | (row & 4095)])*0.125f;
      #pragma unroll
      for (int jj=0;jj<8;jj++) dat.s[jj] = f2bf(elu1(bf2f(dat.s[jj]))*eqc);
      *(uint4*)(qc + a) = dat.v;
    } else if (sec == 1){
      float ekc = __expf(-cb[((size_t)bh2<<12) | (row & 4095)]);
      #pragma unroll
      for (int jj=0;jj<8;jj++) dat.s[jj] = f2bf(elu1(bf2f(dat.s[jj]))*ekc);
      *(uint4*)(kc + a) = dat.v;
    } else {
      *(uint4*)(vc + a) = dat.v;
    }
  }
}

// ---------------- K4: per-chunk S^T MFMA + k~ sums (from chunked k~/v) ----------------
__global__ __launch_bounds__(256) void chunk_sums_kernel(const u16* __restrict__ kc,
    const u16* __restrict__ vc, u16* __restrict__ Stc, float* __restrict__ ksc)
{
  int bid = blockIdx.x;
  __shared__ u16 Kc[4096], Vc[4096];
  __shared__ u16 Ktl[5120], Vtl[5120];     // [2][64][40] padded
  __shared__ float ksr[256];
  int t = threadIdx.x, w = t>>6, lane = t&63;
  {
    const u16* gk = kc + (size_t)bid*4096 + w*1024 + lane*8;
    const u16* gv = vc + (size_t)bid*4096 + w*1024 + lane*8;
    async_ld16(gk,       Kc + w*1024);
    async_ld16(gk + 512, Kc + w*1024 + 512);
    async_ld16(gv,       Vc + w*1024);
    async_ld16(gv + 512, Vc + w*1024 + 512);
  }
  __syncthreads();
  int e = t & 63, jq = t >> 6;
  {
    u16 kv[16] __attribute__((aligned(16)));
    u16 vv[16] __attribute__((aligned(16)));
    float ksum = 0.f;
    #pragma unroll
    for (int jj=0;jj<16;jj++){
      int j = jq*16+jj;
      kv[jj] = Kc[(e>>5)*2048 + j*32 + (e&31)];
      ksum += bf2f(kv[jj]);
      vv[jj] = Vc[(e>>5)*2048 + j*32 + (e&31)];
    }
    int kh2 = jq>>1, jl = (jq&1)*16;
    u16* kt = &Ktl[(kh2*64 + e)*40 + jl];
    u16* vt = &Vtl[(kh2*64 + e)*40 + jl];
    *(uint4*)kt     = *(const uint4*)&kv[0];
    *(uint4*)(kt+8) = *(const uint4*)&kv[8];
    *(uint4*)vt     = *(const uint4*)&vv[0];
    *(uint4*)(vt+8) = *(const uint4*)&vv[8];
    ksr[t] = ksum;
  }
  __syncthreads();
  int r16 = lane & 15, q8 = (lane>>4)*8;
  bf16x8 av[2];
  #pragma unroll
  for (int kh=0;kh<2;kh++)
    av[kh] = *(const bf16x8*)&Vtl[(kh*64 + w*16 + r16)*40 + q8];
  f32x4 acc[4] = {};
  #pragma unroll
  for (int et=0;et<4;et++)
    #pragma unroll
    for (int kh=0;kh<2;kh++){
      bf16x8 bv = *(const bf16x8*)&Ktl[(kh*64 + et*16 + r16)*40 + q8];
      acc[et] = __builtin_amdgcn_mfma_f32_16x16x32_bf16(av[kh], bv, acc[et], 0,0,0);
    }
  #pragma unroll
  for (int et=0;et<4;et++){
    int eh = et>>1, el = (et&1)*16 + r16;
    #pragma unroll
    for (int r=0;r<4;r++){
      int f = w*16 + (lane>>4)*4 + r;
      Stc[((size_t)bid*2 + eh)*2048 + f*32 + el] = f2bf(acc[et][r]);
    }
  }
  if (t < 64) ksc[bid*64 + t] = ksr[t] + ksr[64+t] + ksr[128+t] + ksr[192+t];
}

// ---------------- K5: exclusive prefix over chunks ----------------
__global__ __launch_bounds__(256) void chunk_prefix_kernel(u16* __restrict__ Stc,
    float* __restrict__ ksc)
{
  int blk = blockIdx.x, t = threadIdx.x;
  if (blk < 128){
    int gid = blk*256 + t;                 // 32768 threads
    int bh = gid >> 11, e2 = gid & 2047;
    u32* p = (u32*)Stc + (size_t)bh*131072 + e2;
    float r0 = 0.f, r1 = 0.f;
    #pragma unroll 16
    for (int ch=0; ch<NCH; ch++){
      u32 v = p[ch*2048];
      float lo = bf2f((u16)(v & 0xffffu));
      float hi = bf2f((u16)(v >> 16));
      p[ch*2048] = (u32)f2bf(r0) | ((u32)f2bf(r1) << 16);
      r0 += lo; r1 += hi;
    }
  } else {
    int gid2 = (blk-128)*256 + t;          // 1024 threads = BH*64
    int bh2 = gid2 >> 6, e = gid2 & 63;
    float* kp = ksc + bh2*4096 + e;
    float kr = 0.f;
    #pragma unroll 8
    for (int ch=0; ch<NCH; ch++){
      float v = kp[ch*64]; kp[ch*64] = kr; kr += v;
    }
  }
}

// ---------------- K6: chunk output (Q fragments direct-from-global; V transposed in LDS) ----------------
__global__ __launch_bounds__(256) void chunk_out_kernel(const u16* __restrict__ qc,
    const u16* __restrict__ kc, const u16* __restrict__ vc,
    const u16* __restrict__ Stc, const float* __restrict__ ksc,
    u16* __restrict__ attn)
{
  int bid = blockIdx.x;
  int bh = bid >> 6, ch = bid & 63;
  int b = bh >> 3, h = bh & 7;
  __shared__ u16 Kb_l[4096];
  __shared__ u16 Vc_l[4096];
  __shared__ u16 St_l[4096];
  __shared__ u16 Vt[5120];       // [2][64][40] padded
  __shared__ u16 Ab[4096];       // [jh][l][32]
  __shared__ float R2[320];      // [0..255] den4, [256..319] den
  int t = threadIdx.x, w = t>>6, lane = t&63;
  size_t mbase = (size_t)b*L_ + ch*64;
  {
    const u16* gk = kc  + (size_t)bid*4096 + w*1024 + lane*8;
    const u16* gv = vc  + (size_t)bid*4096 + w*1024 + lane*8;
    const u16* gs = Stc + (size_t)bid*4096 + w*1024 + lane*8;
    async_ld16(gk,       Kb_l + w*1024);
    async_ld16(gk + 512, Kb_l + w*1024 + 512);
    async_ld16(gv,       Vc_l + w*1024);
    async_ld16(gv + 512, Vc_l + w*1024 + 512);
    async_ld16(gs,       St_l + w*1024);
    async_ld16(gs + 512, St_l + w*1024 + 512);
  }
  int r16 = lane & 15, q8 = (lane>>4)*8;
  // Q fragments + kp: issued before the barrier so latency hides under staging
  const u16* qg = qc + (size_t)bid*4096;
  bf16x8 aq[2];
  #pragma unroll
  for (int eh=0;eh<2;eh++)
    aq[eh] = *(const bf16x8*)(qg + eh*2048 + (w*16 + r16)*32 + q8);
  int l4 = t>>2, q4 = t&3;
  int ehd = q4>>1, el0 = (q4&1)*16;
  bf16x8 x1 = *(const bf16x8*)(qg + ehd*2048 + l4*32 + el0);
  bf16x8 x2 = *(const bf16x8*)(qg + ehd*2048 + l4*32 + el0 + 8);
  union { float4 v[4]; float f[16]; } kp;
  #pragma unroll
  for (int qq=0;qq<4;qq++)
    kp.v[qq] = *(const float4*)(ksc + bid*64 + q4*16 + qq*4);
  __syncthreads();   // B1: staging drained
  // V transpose: Vc_l (chunk row layout) -> Vt (padded 40)
  {
    int e = t & 63, jq = t >> 6;
    u16 vv[16] __attribute__((aligned(16)));
    #pragma unroll
    for (int jj=0;jj<16;jj++)
      vv[jj] = Vc_l[(e>>5)*2048 + (jq*16+jj)*32 + (e&31)];
    int jh = jq>>1, jl = (jq&1)*16;
    u16* vt = &Vt[(jh*64 + e)*40 + jl];
    *(uint4*)vt     = *(const uint4*)&vv[0];
    *(uint4*)(vt+8) = *(const uint4*)&vv[8];
  }
  // matmul1: A = Q~ K~^T  (strip l = w*16..w*16+15)
  f32x4 accA[4] = {};
  #pragma unroll
  for (int jt=0;jt<4;jt++)
    #pragma unroll
    for (int eh=0;eh<2;eh++){
      bf16x8 bv = *(const bf16x8*)&Kb_l[(eh*64 + jt*16 + r16)*32 + q8];
      accA[jt] = __builtin_amdgcn_mfma_f32_16x16x32_bf16(aq[eh], bv, accA[jt], 0,0,0);
    }
  // den: q~ . kp part
  float dkp = 0.f;
  #pragma unroll
  for (int i=0;i<8;i++)
    dkp += bf2f((u16)x1[i])*kp.f[i] + bf2f((u16)x2[i])*kp.f[8+i];
  // mask + write A to LDS (bf16, split layout)
  #pragma unroll
  for (int jt=0;jt<4;jt++)
    #pragma unroll
    for (int r=0;r<4;r++){
      int lr = w*16 + ((lane>>4)<<2) + r;
      int j  = jt*16 + r16;
      Ab[((jt>>1)*64 + lr)*32 + (jt&1)*16 + r16] = (j <= lr) ? f2bf(accA[jt][r]) : (u16)0;
    }
  __syncthreads();   // B2: Ab + Vt visible
  // den: masked row-sum of A
  float dA = 0.f;
  {
    int jh2 = q4>>1, jl0 = (q4&1)*16;
    bf16x8 y1 = *(const bf16x8*)&Ab[(jh2*64 + l4)*32 + jl0];
    bf16x8 y2 = *(const bf16x8*)&Ab[(jh2*64 + l4)*32 + jl0 + 8];
    #pragma unroll
    for (int i=0;i<8;i++) dA += bf2f((u16)y1[i]) + bf2f((u16)y2[i]);
  }
  R2[t] = dkp + dA;
  __syncthreads();   // B3
  if (t < 64) R2[256+t] = R2[t*4] + R2[t*4+1] + R2[t*4+2] + R2[t*4+3] + 1e-6f;
  // matmul2: num = A V + Q~ S^T
  bf16x8 aA[2];
  #pragma unroll
  for (int jh=0;jh<2;jh++)
    aA[jh] = *(const bf16x8*)&Ab[(jh*64 + w*16 + r16)*32 + q8];
  f32x4 acc[4] = {};
  #pragma unroll
  for (int ft=0;ft<4;ft++){
    #pragma unroll
    for (int jh=0;jh<2;jh++){
      bf16x8 bv = *(const bf16x8*)&Vt[(jh*64 + ft*16 + r16)*40 + q8];
      acc[ft] = __builtin_amdgcn_mfma_f32_16x16x32_bf16(aA[jh], bv, acc[ft], 0,0,0);
    }
    #pragma unroll
    for (int eh=0;eh<2;eh++){
      bf16x8 bv = *(const bf16x8*)&St_l[(eh*64 + ft*16 + r16)*32 + q8];
      acc[ft] = __builtin_amdgcn_mfma_f32_16x16x32_bf16(aq[eh], bv, acc[ft], 0,0,0);
    }
  }
  __syncthreads();   // B4: den ready
  float inv[4];
  #pragma unroll
  for (int r=0;r<4;r++) inv[r] = 1.f / R2[256 + w*16 + ((lane>>4)<<2) + r];
  #pragma unroll
  for (int ft=0;ft<4;ft++)
    #pragma unroll
    for (int r=0;r<4;r++){
      int lr = w*16 + ((lane>>4)<<2) + r;
      attn[(mbase + lr)*D_ + h*64 + ft*16 + r16] = f2bf(acc[ft][r]*inv[r]);
    }
}

// ---------------- K7: out-projection GEMM fused with RMSNorm epilogue ----------------
__global__ __launch_bounds__(256) void gemm_rms_kernel(const u16* __restrict__ A,
    const u16* __restrict__ W, const float* __restrict__ bias,
    const float* __restrict__ gnorm, float* __restrict__ out)
{
  __shared__ u16 As[2][32*32];
  __shared__ u16 Bs[2][512*32];
  __shared__ float ssq_l[4][32];
  __shared__ float rinv_l[32];
  int m0 = blockIdx.x*32;
  int t = threadIdx.x, wave = t>>6, lane = t&63;
  int wn = wave*128;
  int r16 = lane&15, q8 = (lane>>4)*8;
  f32x4 acc[2][8] = {};
  int scol = (t&3)*8;
  const u16* gB = W + (size_t)(t>>2)*512 + scol;
  const u16* gA = A + (size_t)(m0 + (t>>2))*512 + scol;
  {
    if (wave < 2) async_ld16(gA, As[0] + wave*512);
    #pragma unroll
    for (int it=0; it<8; it++)
      async_ld16(gB + it*32768, Bs[0] + wave*512 + it*2048);
  }
  __syncthreads();
  int cur = 0;
  #pragma unroll 2
  for (int k0=0; k0<512; k0+=32){
    if (k0 < 480){
      if (wave < 2) async_ld16(gA + k0+32, As[cur^1] + wave*512);
      #pragma unroll
      for (int it=0; it<8; it++)
        async_ld16(gB + k0+32 + it*32768, Bs[cur^1] + wave*512 + it*2048);
    }
    bf16x8 af0 = *(const bf16x8*)&As[cur][r16*32 + q8];
    bf16x8 af1 = *(const bf16x8*)&As[cur][(16 + r16)*32 + q8];
    #pragma unroll
    for (int j=0;j<8;j++){
      bf16x8 bv = *(const bf16x8*)&Bs[cur][(wn + j*16 + r16)*32 + q8];
      acc[0][j] = __builtin_amdgcn_mfma_f32_16x16x32_bf16(af0, bv, acc[0][j], 0,0,0);
      acc[1][j] = __builtin_amdgcn_mfma_f32_16x16x32_bf16(af1, bv, acc[1][j], 0,0,0);
    }
    __syncthreads();
    cur ^= 1;
  }
  int g = lane>>4;
  float bv8[8], gv8[8];
  #pragma unroll
  for (int j=0;j<8;j++){ int col = wn + j*16 + r16; bv8[j] = bias[col]; gv8[j] = gnorm[col]; }
  float ssq[2][4] = {};
  #pragma unroll
  for (int i=0;i<2;i++)
    #pragma unroll
    for (int j=0;j<8;j++)
      #pragma unroll
      for (int r=0;r<4;r++){
        float v = acc[i][j][r] + bv8[j];
        acc[i][j][r] = v;
        ssq[i][r] += v*v;
      }
  #pragma unroll
  for (int off=1; off<16; off<<=1)
    #pragma unroll
    for (int i=0;i<2;i++)
      #pragma unroll
      for (int r=0;r<4;r++)
        ssq[i][r] += __shfl_xor(ssq[i][r], off);
  if (r16 == 0){
    #pragma unroll
    for (int i=0;i<2;i++)
      #pragma unroll
      for (int r=0;r<4;r++)
        ssq_l[wave][i*16 + g*4 + r] = ssq[i][r];
  }
  __syncthreads();
  if (t < 32)
    rinv_l[t] = rsqrtf((ssq_l[0][t]+ssq_l[1][t]+ssq_l[2][t]+ssq_l[3][t])*(1.f/512.f) + 1e-8f);
  __syncthreads();
  #pragma unroll
  for (int i=0;i<2;i++)
    #pragma unroll
    for (int r=0;r<4;r++){
      int row = m0 + i*16 + g*4 + r;
      float ri = rinv_l[i*16 + g*4 + r];
      #pragma unroll
      for (int j=0;j<8;j++)
        out[(size_t)row*512 + wn + j*16 + r16] = acc[i][j][r]*ri*gv8[j];
    }
}

extern "C" void kernel_launch(void* const* d_in, const int* in_sizes, int n_in,
                              void* d_out, int out_size, void* d_ws, size_t ws_size,
                              hipStream_t stream)
{
  const float* x     = (const float*)d_in[0];
  const float* w_qkv = (const float*)d_in[1];
  const float* b_qkv = (const float*)d_in[2];
  const float* w_out = (const float*)d_in[3];
  const float* b_out = (const float*)d_in[4];
  const float* w_dec = (const float*)d_in[5];
  const float* b_dec = (const float*)d_in[6];
  const float* gnorm = (const float*)d_in[7];
  float* out = (float*)d_out;

  char* ws = (char*)d_ws;
  u16*   qc   = (u16*)(ws);                    //  8,388,608  chunked q~
  u16*   kc   = (u16*)(ws + 8388608);          //  8,388,608  chunked k~
  u16*   vc   = (u16*)(ws + 16777216);         //  8,388,608  chunked raw v
  u16*   Stc  = (u16*)(ws + 25165824);         //  8,388,608  chunked [bid][eh][f][32]
  float* ksc  = (float*)(ws + 33554432);       //    262,144
  float* ll   = (float*)(ws + 33816576);       //    262,144
  float* cb   = (float*)(ws + 34078720);       //    262,144
  u16*   xb   = (u16*)(ws + 34340864);         //  8,388,608  (attn reuses)
  u16*   qwb  = (u16*)(ws + 42729472);         //  1,572,864
  u16*   owb  = (u16*)(ws + 44302336);         //    524,288  total 44,826,624
  u16*   attn = xb;

  decay_conv_kernel<<<dim3(3072), dim3(256), 0, stream>>>(x, w_dec, b_dec, w_qkv, w_out,
                                                          ll, xb, qwb, owb);
  scan_kernel<<<dim3(BH), dim3(256), 0, stream>>>(ll, cb);
  gemm_qkv_fused<<<dim3(TD/128, M_/128), dim3(256), 0, stream>>>(xb, qwb, b_qkv, cb, qc, kc, vc);
  chunk_sums_kernel<<<dim3(BH*NCH), dim3(256), 0, stream>>>(kc, vc, Stc, ksc);
  chunk_prefix_kernel<<<dim3(132), dim3(256), 0, stream>>>(Stc, ksc);
  chunk_out_kernel<<<dim3(BH*NCH), dim3(256), 0, stream>>>(qc, kc, vc, Stc, ksc, attn);
  gemm_rms_kernel<<<dim3(M_/32), dim3(256), 0, stream>>>(attn, owb, b_out, gnorm, out);
}

// Round 6
// 152.549 us; speedup vs baseline: 1.0665x; 1.0122x over previous
//
#include <hip/hip_runtime.h>

typedef unsigned short u16;
typedef unsigned int u32;

#define B_ 2
#define L_ 4096
#define D_ 512
#define H_ 8
#define E_ 64
#define M_ (B_*L_)        // 8192 rows
#define TD (3*D_)         // 1536
#define NCH (L_/64)       // 64 chunks of 64 per sequence
#define BH (B_*H_)        // 16

typedef short bf16x8 __attribute__((ext_vector_type(8)));
typedef float f32x4 __attribute__((ext_vector_type(4)));

__device__ __forceinline__ float bf2f(u16 u){ return __uint_as_float(((u32)u)<<16); }
__device__ __forceinline__ u16 f2bf(float f){
  u32 u = __float_as_uint(f);
  u32 r = u + 0x7FFFu + ((u>>16)&1u);   // RNE; inputs finite
  return (u16)(r>>16);
}
__device__ __forceinline__ float elu1(float v){ return v>0.f ? v+1.f : __expf(v); }

__device__ __forceinline__ void async_ld16(const u16* g, u16* l){
  __builtin_amdgcn_global_load_lds(
      (const __attribute__((address_space(1))) void*)g,
      (__attribute__((address_space(3))) void*)l, 16, 0, 0);
}

// ---------------- K1: decay logits + x->bf16 + weight conversions ----------------
__global__ __launch_bounds__(256) void decay_conv_kernel(const float* __restrict__ x,
    const float* __restrict__ dw, const float* __restrict__ db,
    const float* __restrict__ qw, const float* __restrict__ ow,
    float* __restrict__ ll, u16* __restrict__ xb,
    u16* __restrict__ qwb, u16* __restrict__ owb)
{
  int blk = blockIdx.x;
  if (blk < 2048){
    int wv = threadIdx.x>>6, lane = threadIdx.x&63;
    int m = blk*4 + wv;
    float xr[8];
    #pragma unroll
    for (int i=0;i<8;i++) xr[i] = x[(size_t)m*D_ + lane + 64*i];
    #pragma unroll
    for (int i=0;i<8;i++) xb[(size_t)m*D_ + lane + 64*i] = f2bf(xr[i]);
    int b = m >> 12, l = m & (L_-1);
    float acc8[8];
    #pragma unroll
    for (int h=0; h<8; h++){
      float a = 0.f;
      #pragma unroll
      for (int i=0;i<8;i++) a += xr[i]*dw[h*D_ + lane + 64*i];
      acc8[h] = a;
    }
    float s4[4];
    #pragma unroll
    for (int i=0;i<4;i++){
      float a = acc8[2*i], bb = acc8[2*i+1];
      bool odd = lane & 1;
      float keep = odd ? bb : a;
      float send = odd ? a : bb;
      s4[i] = keep + __shfl_xor(send, 1);
    }
    float s2[2];
    #pragma unroll
    for (int j=0;j<2;j++){
      float a = s4[2*j], bb = s4[2*j+1];
      bool sel = (lane>>1) & 1;
      float keep = sel ? bb : a;
      float send = sel ? a : bb;
      s2[j] = keep + __shfl_xor(send, 2);
    }
    float r;
    {
      bool sel = (lane>>2) & 1;
      float keep = sel ? s2[1] : s2[0];
      float send = sel ? s2[0] : s2[1];
      r = keep + __shfl_xor(send, 4);
    }
    r += __shfl_xor(r, 8);
    r += __shfl_xor(r, 16);
    r += __shfl_xor(r, 32);
    if (lane < 8){
      float z = r + db[lane];
      float lam = 0.9f + 0.1f/(1.f + __expf(-z));
      ll[((b*H_+lane)*L_) + l] = __logf(lam);
    }
  } else {
    int gid = (blk-2048)*256 + threadIdx.x;   // 262144 float4 groups
    const float* src; u16* dst; int off;
    if (gid < 196608){ src = qw; dst = qwb; off = gid; }
    else { src = ow; dst = owb; off = gid - 196608; }
    float4 v = ((const float4*)src)[off];
    ushort4 o; o.x=f2bf(v.x); o.y=f2bf(v.y); o.z=f2bf(v.z); o.w=f2bf(v.w);
    ((ushort4*)dst)[off] = o;
  }
}

// ---------------- K2: inclusive scan over L (shfl-based), clip to [-50,50] ----------------
__global__ __launch_bounds__(256) void scan_kernel(const float* __restrict__ ll,
    float* __restrict__ cb)
{
  int bh = blockIdx.x, t = threadIdx.x;
  int lane = t & 63, wv = t >> 6;
  const float* p = ll + (size_t)bh*L_ + t*16;
  float s[16];
  #pragma unroll
  for (int q=0;q<4;q++){
    float4 v = *(const float4*)(p + q*4);
    s[q*4+0]=v.x; s[q*4+1]=v.y; s[q*4+2]=v.z; s[q*4+3]=v.w;
  }
  #pragma unroll
  for (int i=1;i<16;i++) s[i] += s[i-1];
  float tot = s[15];
  float ws = tot;
  #pragma unroll
  for (int off=1; off<64; off<<=1){
    float tmp = __shfl_up(ws, off);
    if (lane >= off) ws += tmp;
  }
  __shared__ float wsum[4];
  if (lane == 63) wsum[wv] = ws;
  __syncthreads();
  float base = 0.f;
  #pragma unroll
  for (int w2=0; w2<3; w2++) if (w2 < wv) base += wsum[w2];
  float ex = base + ws - tot;
  float* c = cb + (size_t)bh*L_ + t*16;
  #pragma unroll
  for (int i=0;i<16;i++) c[i] = fminf(50.f, fmaxf(-50.f, ex + s[i]));
}

// ---------------- K3: QKV GEMM, 3-buffer ring + counted vmcnt (T3/T4) ----------------
// Stage k+2 after the per-step barrier; wait vmcnt(4) (next tile's 4 loads stay in
// flight). Single raw barrier per K-step. Epilogue v2 (LDS-staged) unchanged.
__global__ __launch_bounds__(256) void gemm_qkv_fused(const u16* __restrict__ A,
    const u16* __restrict__ W, const float* __restrict__ bias,
    const float* __restrict__ cb,
    u16* __restrict__ qc, u16* __restrict__ kc, u16* __restrict__ vc)
{
  __shared__ u16 SM[24576];            // 49152 B: 3 ring bufs (A 4096 | B 4096 u16 each); epilogue Ct[128][136]
  const int K = 512;
  int n0 = blockIdx.x*128, m0 = blockIdx.y*128;
  int t = threadIdx.x, wave = t>>6, lane = t&63;
  int wm = (wave>>1)*64, wn = (wave&1)*64;
  f32x4 acc[4][4] = {};
  int srow = wave*32 + (lane>>2);
  int scol = (lane&3)*8;
  const u16* gA = A + (size_t)(m0+srow)*K + scol;
  const u16* gB = W + (size_t)(n0+srow)*K + scol;
  int q8 = (lane>>4)*8, r16 = lane&15;
  auto STAGE = [&](u16* buf, int k0){
    u16* lA = buf + wave*1024;
    u16* lB = buf + 4096 + wave*1024;
    async_ld16(gA + k0,                lA);
    async_ld16(gA + k0 + 16*(size_t)K, lA + 512);
    async_ld16(gB + k0,                lB);
    async_ld16(gB + k0 + 16*(size_t)K, lB + 512);
  };
  u16 *cB = SM, *nB = SM + 8192, *tB = SM + 16384;
  STAGE(cB, 0);
  STAGE(nB, 32);
  for (int k0=0; k0<K; k0+=32){
    if (k0 + 32 < K) asm volatile("s_waitcnt vmcnt(4)" ::: "memory");
    else             asm volatile("s_waitcnt vmcnt(0)" ::: "memory");
    __builtin_amdgcn_s_barrier();
    if (k0 + 64 < K) STAGE(tB, k0 + 64);
    bf16x8 af[4], bfr[4];
    #pragma unroll
    for (int i=0;i<4;i++) af[i]  = *(const bf16x8*)&cB[(wm + i*16 + r16)*32 + q8];
    #pragma unroll
    for (int j=0;j<4;j++) bfr[j] = *(const bf16x8*)&cB[4096 + (wn + j*16 + r16)*32 + q8];
    #pragma unroll
    for (int i=0;i<4;i++)
      #pragma unroll
      for (int j=0;j<4;j++)
        acc[i][j] = __builtin_amdgcn_mfma_f32_16x16x32_bf16(af[i], bfr[j], acc[i][j], 0,0,0);
    u16* tmp = cB; cB = nB; nB = tB; tB = tmp;
  }
  __syncthreads();                     // all K-loop LDS reads done; SM reusable
  // ---- epilogue v2 ----
  int g = lane>>4;
  // 1) acc+bias -> Ct[128][136] bf16
  #pragma unroll
  for (int j=0;j<4;j++){
    int col = wn + j*16 + r16;
    float bv = bias[n0 + col];
    #pragma unroll
    for (int i=0;i<4;i++){
      int rbase = wm + i*16 + g*4;
      #pragma unroll
      for (int r=0;r<4;r++)
        SM[(rbase+r)*136 + col] = f2bf(acc[i][j][r] + bv);
    }
  }
  __syncthreads();
  // 2) transform + chunked uint4 stores
  int sec = n0 >> 9;                   // 0=q, 1=k, 2=v (uniform per block)
  #pragma unroll
  for (int u=0;u<8;u++){
    int idx = t + 256*u;               // 2048 uint4 groups
    int rloc = idx >> 4;               // 0..127
    int colg = (idx & 15) * 8;         // 0..120
    int row = m0 + rloc;
    int nn = (n0 + colg) & 511;
    int h2 = nn>>6, e0 = nn&63;
    int bh2 = ((row>>12)<<3) | h2;
    int bid = (bh2<<6) | ((row>>6)&63);
    int l6 = row & 63;
    union { uint4 v; u16 s[8]; } dat;
    dat.v = *(const uint4*)&SM[rloc*136 + colg];
    size_t a = ((size_t)(bid*2 + (e0>>5)))*2048 + (size_t)l6*32 + (e0&31);
    if (sec == 0){
      float eqc = __expf(cb[((size_t)bh2<<12) | (row & 4095)])*0.125f;
      #pragma unroll
      for (int jj=0;jj<8;jj++) dat.s[jj] = f2bf(elu1(bf2f(dat.s[jj]))*eqc);
      *(uint4*)(qc + a) = dat.v;
    } else if (sec == 1){
      float ekc = __expf(-cb[((size_t)bh2<<12) | (row & 4095)]);
      #pragma unroll
      for (int jj=0;jj<8;jj++) dat.s[jj] = f2bf(elu1(bf2f(dat.s[jj]))*ekc);
      *(uint4*)(kc + a) = dat.v;
    } else {
      *(uint4*)(vc + a) = dat.v;
    }
  }
}

// ---------------- K4: per-chunk S^T MFMA + k~ sums (from chunked k~/v) ----------------
__global__ __launch_bounds__(256) void chunk_sums_kernel(const u16* __restrict__ kc,
    const u16* __restrict__ vc, u16* __restrict__ Stc, float* __restrict__ ksc)
{
  int bid = blockIdx.x;
  __shared__ u16 Kc[4096], Vc[4096];
  __shared__ u16 Ktl[5120], Vtl[5120];     // [2][64][40] padded
  __shared__ float ksr[256];
  int t = threadIdx.x, w = t>>6, lane = t&63;
  {
    const u16* gk = kc + (size_t)bid*4096 + w*1024 + lane*8;
    const u16* gv = vc + (size_t)bid*4096 + w*1024 + lane*8;
    async_ld16(gk,       Kc + w*1024);
    async_ld16(gk + 512, Kc + w*1024 + 512);
    async_ld16(gv,       Vc + w*1024);
    async_ld16(gv + 512, Vc + w*1024 + 512);
  }
  __syncthreads();
  int e = t & 63, jq = t >> 6;
  {
    u16 kv[16] __attribute__((aligned(16)));
    u16 vv[16] __attribute__((aligned(16)));
    float ksum = 0.f;
    #pragma unroll
    for (int jj=0;jj<16;jj++){
      int j = jq*16+jj;
      kv[jj] = Kc[(e>>5)*2048 + j*32 + (e&31)];
      ksum += bf2f(kv[jj]);
      vv[jj] = Vc[(e>>5)*2048 + j*32 + (e&31)];
    }
    int kh2 = jq>>1, jl = (jq&1)*16;
    u16* kt = &Ktl[(kh2*64 + e)*40 + jl];
    u16* vt = &Vtl[(kh2*64 + e)*40 + jl];
    *(uint4*)kt     = *(const uint4*)&kv[0];
    *(uint4*)(kt+8) = *(const uint4*)&kv[8];
    *(uint4*)vt     = *(const uint4*)&vv[0];
    *(uint4*)(vt+8) = *(const uint4*)&vv[8];
    ksr[t] = ksum;
  }
  __syncthreads();
  int r16 = lane & 15, q8 = (lane>>4)*8;
  bf16x8 av[2];
  #pragma unroll
  for (int kh=0;kh<2;kh++)
    av[kh] = *(const bf16x8*)&Vtl[(kh*64 + w*16 + r16)*40 + q8];
  f32x4 acc[4] = {};
  #pragma unroll
  for (int et=0;et<4;et++)
    #pragma unroll
    for (int kh=0;kh<2;kh++){
      bf16x8 bv = *(const bf16x8*)&Ktl[(kh*64 + et*16 + r16)*40 + q8];
      acc[et] = __builtin_amdgcn_mfma_f32_16x16x32_bf16(av[kh], bv, acc[et], 0,0,0);
    }
  #pragma unroll
  for (int et=0;et<4;et++){
    int eh = et>>1, el = (et&1)*16 + r16;
    #pragma unroll
    for (int r=0;r<4;r++){
      int f = w*16 + (lane>>4)*4 + r;
      Stc[((size_t)bid*2 + eh)*2048 + f*32 + el] = f2bf(acc[et][r]);
    }
  }
  if (t < 64) ksc[bid*64 + t] = ksr[t] + ksr[64+t] + ksr[128+t] + ksr[192+t];
}

// ---------------- K5: exclusive prefix over chunks ----------------
__global__ __launch_bounds__(256) void chunk_prefix_kernel(u16* __restrict__ Stc,
    float* __restrict__ ksc)
{
  int blk = blockIdx.x, t = threadIdx.x;
  if (blk < 128){
    int gid = blk*256 + t;                 // 32768 threads
    int bh = gid >> 11, e2 = gid & 2047;
    u32* p = (u32*)Stc + (size_t)bh*131072 + e2;
    float r0 = 0.f, r1 = 0.f;
    #pragma unroll 16
    for (int ch=0; ch<NCH; ch++){
      u32 v = p[ch*2048];
      float lo = bf2f((u16)(v & 0xffffu));
      float hi = bf2f((u16)(v >> 16));
      p[ch*2048] = (u32)f2bf(r0) | ((u32)f2bf(r1) << 16);
      r0 += lo; r1 += hi;
    }
  } else {
    int gid2 = (blk-128)*256 + t;          // 1024 threads = BH*64
    int bh2 = gid2 >> 6, e = gid2 & 63;
    float* kp = ksc + bh2*4096 + e;
    float kr = 0.f;
    #pragma unroll 8
    for (int ch=0; ch<NCH; ch++){
      float v = kp[ch*64]; kp[ch*64] = kr; kr += v;
    }
  }
}

// ---------------- K6: chunk output (Q fragments direct-from-global; V transposed in LDS) ----------------
__global__ __launch_bounds__(256) void chunk_out_kernel(const u16* __restrict__ qc,
    const u16* __restrict__ kc, const u16* __restrict__ vc,
    const u16* __restrict__ Stc, const float* __restrict__ ksc,
    u16* __restrict__ attn)
{
  int bid = blockIdx.x;
  int bh = bid >> 6, ch = bid & 63;
  int b = bh >> 3, h = bh & 7;
  __shared__ u16 Kb_l[4096];
  __shared__ u16 Vc_l[4096];
  __shared__ u16 St_l[4096];
  __shared__ u16 Vt[5120];       // [2][64][40] padded
  __shared__ u16 Ab[4096];       // [jh][l][32]
  __shared__ float R2[320];      // [0..255] den4, [256..319] den
  int t = threadIdx.x, w = t>>6, lane = t&63;
  size_t mbase = (size_t)b*L_ + ch*64;
  {
    const u16* gk = kc  + (size_t)bid*4096 + w*1024 + lane*8;
    const u16* gv = vc  + (size_t)bid*4096 + w*1024 + lane*8;
    const u16* gs = Stc + (size_t)bid*4096 + w*1024 + lane*8;
    async_ld16(gk,       Kb_l + w*1024);
    async_ld16(gk + 512, Kb_l + w*1024 + 512);
    async_ld16(gv,       Vc_l + w*1024);
    async_ld16(gv + 512, Vc_l + w*1024 + 512);
    async_ld16(gs,       St_l + w*1024);
    async_ld16(gs + 512, St_l + w*1024 + 512);
  }
  int r16 = lane & 15, q8 = (lane>>4)*8;
  // Q fragments + kp: issued before the barrier so latency hides under staging
  const u16* qg = qc + (size_t)bid*4096;
  bf16x8 aq[2];
  #pragma unroll
  for (int eh=0;eh<2;eh++)
    aq[eh] = *(const bf16x8*)(qg + eh*2048 + (w*16 + r16)*32 + q8);
  int l4 = t>>2, q4 = t&3;
  int ehd = q4>>1, el0 = (q4&1)*16;
  bf16x8 x1 = *(const bf16x8*)(qg + ehd*2048 + l4*32 + el0);
  bf16x8 x2 = *(const bf16x8*)(qg + ehd*2048 + l4*32 + el0 + 8);
  union { float4 v[4]; float f[16]; } kp;
  #pragma unroll
  for (int qq=0;qq<4;qq++)
    kp.v[qq] = *(const float4*)(ksc + bid*64 + q4*16 + qq*4);
  __syncthreads();   // B1: staging drained
  // V transpose: Vc_l (chunk row layout) -> Vt (padded 40)
  {
    int e = t & 63, jq = t >> 6;
    u16 vv[16] __attribute__((aligned(16)));
    #pragma unroll
    for (int jj=0;jj<16;jj++)
      vv[jj] = Vc_l[(e>>5)*2048 + (jq*16+jj)*32 + (e&31)];
    int jh = jq>>1, jl = (jq&1)*16;
    u16* vt = &Vt[(jh*64 + e)*40 + jl];
    *(uint4*)vt     = *(const uint4*)&vv[0];
    *(uint4*)(vt+8) = *(const uint4*)&vv[8];
  }
  // matmul1: A = Q~ K~^T  (strip l = w*16..w*16+15)
  f32x4 accA[4] = {};
  #pragma unroll
  for (int jt=0;jt<4;jt++)
    #pragma unroll
    for (int eh=0;eh<2;eh++){
      bf16x8 bv = *(const bf16x8*)&Kb_l[(eh*64 + jt*16 + r16)*32 + q8];
      accA[jt] = __builtin_amdgcn_mfma_f32_16x16x32_bf16(aq[eh], bv, accA[jt], 0,0,0);
    }
  // den: q~ . kp part
  float dkp = 0.f;
  #pragma unroll
  for (int i=0;i<8;i++)
    dkp += bf2f((u16)x1[i])*kp.f[i] + bf2f((u16)x2[i])*kp.f[8+i];
  // mask + write A to LDS (bf16, split layout)
  #pragma unroll
  for (int jt=0;jt<4;jt++)
    #pragma unroll
    for (int r=0;r<4;r++){
      int lr = w*16 + ((lane>>4)<<2) + r;
      int j  = jt*16 + r16;
      Ab[((jt>>1)*64 + lr)*32 + (jt&1)*16 + r16] = (j <= lr) ? f2bf(accA[jt][r]) : (u16)0;
    }
  __syncthreads();   // B2: Ab + Vt visible
  // den: masked row-sum of A
  float dA = 0.f;
  {
    int jh2 = q4>>1, jl0 = (q4&1)*16;
    bf16x8 y1 = *(const bf16x8*)&Ab[(jh2*64 + l4)*32 + jl0];
    bf16x8 y2 = *(const bf16x8*)&Ab[(jh2*64 + l4)*32 + jl0 + 8];
    #pragma unroll
    for (int i=0;i<8;i++) dA += bf2f((u16)y1[i]) + bf2f((u16)y2[i]);
  }
  R2[t] = dkp + dA;
  __syncthreads();   // B3
  if (t < 64) R2[256+t] = R2[t*4] + R2[t*4+1] + R2[t*4+2] + R2[t*4+3] + 1e-6f;
  // matmul2: num = A V + Q~ S^T
  bf16x8 aA[2];
  #pragma unroll
  for (int jh=0;jh<2;jh++)
    aA[jh] = *(const bf16x8*)&Ab[(jh*64 + w*16 + r16)*32 + q8];
  f32x4 acc[4] = {};
  #pragma unroll
  for (int ft=0;ft<4;ft++){
    #pragma unroll
    for (int jh=0;jh<2;jh++){
      bf16x8 bv = *(const bf16x8*)&Vt[(jh*64 + ft*16 + r16)*40 + q8];
      acc[ft] = __builtin_amdgcn_mfma_f32_16x16x32_bf16(aA[jh], bv, acc[ft], 0,0,0);
    }
    #pragma unroll
    for (int eh=0;eh<2;eh++){
      bf16x8 bv = *(const bf16x8*)&St_l[(eh*64 + ft*16 + r16)*32 + q8];
      acc[ft] = __builtin_amdgcn_mfma_f32_16x16x32_bf16(aq[eh], bv, acc[ft], 0,0,0);
    }
  }
  __syncthreads();   // B4: den ready
  float inv[4];
  #pragma unroll
  for (int r=0;r<4;r++) inv[r] = 1.f / R2[256 + w*16 + ((lane>>4)<<2) + r];
  #pragma unroll
  for (int ft=0;ft<4;ft++)
    #pragma unroll
    for (int r=0;r<4;r++){
      int lr = w*16 + ((lane>>4)<<2) + r;
      attn[(mbase + lr)*D_ + h*64 + ft*16 + r16] = f2bf(acc[ft][r]*inv[r]);
    }
}

// ---------------- K7: out-proj GEMM + RMSNorm, counted-wait single-barrier loop ----------------
__global__ __launch_bounds__(256) void gemm_rms_kernel(const u16* __restrict__ A,
    const u16* __restrict__ W, const float* __restrict__ bias,
    const float* __restrict__ gnorm, float* __restrict__ out)
{
  __shared__ u16 As[2][1024];
  __shared__ u16 Bs[2][16384];
  __shared__ float ssq_l[4][32];
  __shared__ float rinv_l[32];
  int m0 = blockIdx.x*32;
  int t = threadIdx.x, wave = t>>6, lane = t&63;
  int wn = wave*128;
  int r16 = lane&15, q8 = (lane>>4)*8;
  f32x4 acc[2][8] = {};
  int scol = (t&3)*8;
  const u16* gB = W + (size_t)(t>>2)*512 + scol;
  const u16* gA = A + (size_t)(m0 + (t>>2))*512 + scol;
  {
    if (wave < 2) async_ld16(gA, As[0] + wave*512);
    #pragma unroll
    for (int it=0; it<8; it++)
      async_ld16(gB + it*32768, Bs[0] + wave*512 + it*2048);
  }
  int cur = 0;
  for (int k0=0; k0<512; k0+=32){
    asm volatile("s_waitcnt vmcnt(0)" ::: "memory");
    __builtin_amdgcn_s_barrier();
    if (k0 < 480){
      if (wave < 2) async_ld16(gA + k0+32, As[cur^1] + wave*512);
      #pragma unroll
      for (int it=0; it<8; it++)
        async_ld16(gB + k0+32 + it*32768, Bs[cur^1] + wave*512 + it*2048);
    }
    bf16x8 af0 = *(const bf16x8*)&As[cur][r16*32 + q8];
    bf16x8 af1 = *(const bf16x8*)&As[cur][(16 + r16)*32 + q8];
    #pragma unroll
    for (int j=0;j<8;j++){
      bf16x8 bv = *(const bf16x8*)&Bs[cur][(wn + j*16 + r16)*32 + q8];
      acc[0][j] = __builtin_amdgcn_mfma_f32_16x16x32_bf16(af0, bv, acc[0][j], 0,0,0);
      acc[1][j] = __builtin_amdgcn_mfma_f32_16x16x32_bf16(af1, bv, acc[1][j], 0,0,0);
    }
    cur ^= 1;
  }
  int g = lane>>4;
  float bv8[8], gv8[8];
  #pragma unroll
  for (int j=0;j<8;j++){ int col = wn + j*16 + r16; bv8[j] = bias[col]; gv8[j] = gnorm[col]; }
  float ssq[2][4] = {};
  #pragma unroll
  for (int i=0;i<2;i++)
    #pragma unroll
    for (int j=0;j<8;j++)
      #pragma unroll
      for (int r=0;r<4;r++){
        float v = acc[i][j][r] + bv8[j];
        acc[i][j][r] = v;
        ssq[i][r] += v*v;
      }
  #pragma unroll
  for (int off=1; off<16; off<<=1)
    #pragma unroll
    for (int i=0;i<2;i++)
      #pragma unroll
      for (int r=0;r<4;r++)
        ssq[i][r] += __shfl_xor(ssq[i][r], off);
  if (r16 == 0){
    #pragma unroll
    for (int i=0;i<2;i++)
      #pragma unroll
      for (int r=0;r<4;r++)
        ssq_l[wave][i*16 + g*4 + r] = ssq[i][r];
  }
  __syncthreads();
  if (t < 32)
    rinv_l[t] = rsqrtf((ssq_l[0][t]+ssq_l[1][t]+ssq_l[2][t]+ssq_l[3][t])*(1.f/512.f) + 1e-8f);
  __syncthreads();
  #pragma unroll
  for (int i=0;i<2;i++)
    #pragma unroll
    for (int r=0;r<4;r++){
      int row = m0 + i*16 + g*4 + r;
      float ri = rinv_l[i*16 + g*4 + r];
      #pragma unroll
      for (int j=0;j<8;j++)
        out[(size_t)row*512 + wn + j*16 + r16] = acc[i][j][r]*ri*gv8[j];
    }
}

extern "C" void kernel_launch(void* const* d_in, const int* in_sizes, int n_in,
                              void* d_out, int out_size, void* d_ws, size_t ws_size,
                              hipStream_t stream)
{
  const float* x     = (const float*)d_in[0];
  const float* w_qkv = (const float*)d_in[1];
  const float* b_qkv = (const float*)d_in[2];
  const float* w_out = (const float*)d_in[3];
  const float* b_out = (const float*)d_in[4];
  const float* w_dec = (const float*)d_in[5];
  const float* b_dec = (const float*)d_in[6];
  const float* gnorm = (const float*)d_in[7];
  float* out = (float*)d_out;

  char* ws = (char*)d_ws;
  u16*   qc   = (u16*)(ws);                    //  8,388,608  chunked q~
  u16*   kc   = (u16*)(ws + 8388608);          //  8,388,608  chunked k~
  u16*   vc   = (u16*)(ws + 16777216);         //  8,388,608  chunked raw v
  u16*   Stc  = (u16*)(ws + 25165824);         //  8,388,608  chunked [bid][eh][f][32]
  float* ksc  = (float*)(ws + 33554432);       //    262,144
  float* ll   = (float*)(ws + 33816576);       //    262,144
  float* cb   = (float*)(ws + 34078720);       //    262,144
  u16*   xb   = (u16*)(ws + 34340864);         //  8,388,608  (attn reuses)
  u16*   qwb  = (u16*)(ws + 42729472);         //  1,572,864
  u16*   owb  = (u16*)(ws + 44302336);         //    524,288  total 44,826,624
  u16*   attn = xb;

  decay_conv_kernel<<<dim3(3072), dim3(256), 0, stream>>>(x, w_dec, b_dec, w_qkv, w_out,
                                                          ll, xb, qwb, owb);
  scan_kernel<<<dim3(BH), dim3(256), 0, stream>>>(ll, cb);
  gemm_qkv_fused<<<dim3(TD/128, M_/128), dim3(256), 0, stream>>>(xb, qwb, b_qkv, cb, qc, kc, vc);
  chunk_sums_kernel<<<dim3(BH*NCH), dim3(256), 0, stream>>>(kc, vc, Stc, ksc);
  chunk_prefix_kernel<<<dim3(132), dim3(256), 0, stream>>>(Stc, ksc);
  chunk_out_kernel<<<dim3(BH*NCH), dim3(256), 0, stream>>>(qc, kc, vc, Stc, ksc, attn);
  gemm_rms_kernel<<<dim3(M_/32), dim3(256), 0, stream>>>(attn, owb, b_out, gnorm, out);
}

// Round 7
// 150.694 us; speedup vs baseline: 1.0796x; 1.0123x over previous
//
#include <hip/hip_runtime.h>

typedef unsigned short u16;
typedef unsigned int u32;

#define B_ 2
#define L_ 4096
#define D_ 512
#define H_ 8
#define E_ 64
#define M_ (B_*L_)        // 8192 rows
#define TD (3*D_)         // 1536
#define NCH (L_/64)       // 64 chunks of 64 per sequence
#define BH (B_*H_)        // 16

typedef short bf16x8 __attribute__((ext_vector_type(8)));
typedef float f32x4 __attribute__((ext_vector_type(4)));

__device__ __forceinline__ float bf2f(u16 u){ return __uint_as_float(((u32)u)<<16); }
__device__ __forceinline__ u16 f2bf(float f){
  u32 u = __float_as_uint(f);
  u32 r = u + 0x7FFFu + ((u>>16)&1u);   // RNE; inputs finite
  return (u16)(r>>16);
}
__device__ __forceinline__ float elu1(float v){ return v>0.f ? v+1.f : __expf(v); }

__device__ __forceinline__ void async_ld16(const u16* g, u16* l){
  __builtin_amdgcn_global_load_lds(
      (const __attribute__((address_space(1))) void*)g,
      (__attribute__((address_space(3))) void*)l, 16, 0, 0);
}

// ---------------- K1: decay logits + x->bf16 + weight conversions ----------------
// Row remap: block i (XCD i%8) handles rows [ (i%8)*1024 + (i/8)*4 , +4 ) so that
// xb rows land on the same XCD's L2 that K3 will read them from.
__global__ __launch_bounds__(256) void decay_conv_kernel(const float* __restrict__ x,
    const float* __restrict__ dw, const float* __restrict__ db,
    const float* __restrict__ qw, const float* __restrict__ ow,
    float* __restrict__ ll, u16* __restrict__ xb,
    u16* __restrict__ qwb, u16* __restrict__ owb)
{
  int blk = blockIdx.x;
  if (blk < 2048){
    int wv = threadIdx.x>>6, lane = threadIdx.x&63;
    int m = ((blk&7)<<10) + ((blk>>3)<<2) + wv;   // XCD-aligned with K3 m-panels
    float xr[8];
    #pragma unroll
    for (int i=0;i<8;i++) xr[i] = x[(size_t)m*D_ + lane + 64*i];
    #pragma unroll
    for (int i=0;i<8;i++) xb[(size_t)m*D_ + lane + 64*i] = f2bf(xr[i]);
    int b = m >> 12, l = m & (L_-1);
    float acc8[8];
    #pragma unroll
    for (int h=0; h<8; h++){
      float a = 0.f;
      #pragma unroll
      for (int i=0;i<8;i++) a += xr[i]*dw[h*D_ + lane + 64*i];
      acc8[h] = a;
    }
    float s4[4];
    #pragma unroll
    for (int i=0;i<4;i++){
      float a = acc8[2*i], bb = acc8[2*i+1];
      bool odd = lane & 1;
      float keep = odd ? bb : a;
      float send = odd ? a : bb;
      s4[i] = keep + __shfl_xor(send, 1);
    }
    float s2[2];
    #pragma unroll
    for (int j=0;j<2;j++){
      float a = s4[2*j], bb = s4[2*j+1];
      bool sel = (lane>>1) & 1;
      float keep = sel ? bb : a;
      float send = sel ? a : bb;
      s2[j] = keep + __shfl_xor(send, 2);
    }
    float r;
    {
      bool sel = (lane>>2) & 1;
      float keep = sel ? s2[1] : s2[0];
      float send = sel ? s2[0] : s2[1];
      r = keep + __shfl_xor(send, 4);
    }
    r += __shfl_xor(r, 8);
    r += __shfl_xor(r, 16);
    r += __shfl_xor(r, 32);
    if (lane < 8){
      float z = r + db[lane];
      float lam = 0.9f + 0.1f/(1.f + __expf(-z));
      ll[((b*H_+lane)*L_) + l] = __logf(lam);
    }
  } else {
    int gid = (blk-2048)*256 + threadIdx.x;   // 262144 float4 groups
    const float* src; u16* dst; int off;
    if (gid < 196608){ src = qw; dst = qwb; off = gid; }
    else { src = ow; dst = owb; off = gid - 196608; }
    float4 v = ((const float4*)src)[off];
    ushort4 o; o.x=f2bf(v.x); o.y=f2bf(v.y); o.z=f2bf(v.z); o.w=f2bf(v.w);
    ((ushort4*)dst)[off] = o;
  }
}

// ---------------- K2: inclusive scan over L (shfl-based), clip to [-50,50] ----------------
__global__ __launch_bounds__(256) void scan_kernel(const float* __restrict__ ll,
    float* __restrict__ cb)
{
  int bh = blockIdx.x, t = threadIdx.x;
  int lane = t & 63, wv = t >> 6;
  const float* p = ll + (size_t)bh*L_ + t*16;
  float s[16];
  #pragma unroll
  for (int q=0;q<4;q++){
    float4 v = *(const float4*)(p + q*4);
    s[q*4+0]=v.x; s[q*4+1]=v.y; s[q*4+2]=v.z; s[q*4+3]=v.w;
  }
  #pragma unroll
  for (int i=1;i<16;i++) s[i] += s[i-1];
  float tot = s[15];
  float ws = tot;
  #pragma unroll
  for (int off=1; off<64; off<<=1){
    float tmp = __shfl_up(ws, off);
    if (lane >= off) ws += tmp;
  }
  __shared__ float wsum[4];
  if (lane == 63) wsum[wv] = ws;
  __syncthreads();
  float base = 0.f;
  #pragma unroll
  for (int w2=0; w2<3; w2++) if (w2 < wv) base += wsum[w2];
  float ex = base + ws - tot;
  float* c = cb + (size_t)bh*L_ + t*16;
  #pragma unroll
  for (int i=0;i<16;i++) c[i] = fminf(50.f, fmaxf(-50.f, ex + s[i]));
}

// ---------------- K3: QKV GEMM, XCD-local block remap + 3-ring counted vmcnt ----------------
// Block i -> XCD i%8 owns m-panels [8x, 8x+8) x all 12 n-blocks: per-XCD L2 working
// set = 1 MB A-panels + 1.5 MB B = 2.5 MB <= 4 MB -> all 12x/64x panel re-reads L2-hit.
__global__ __launch_bounds__(256) void gemm_qkv_fused(const u16* __restrict__ A,
    const u16* __restrict__ W, const float* __restrict__ bias,
    const float* __restrict__ cb,
    u16* __restrict__ qc, u16* __restrict__ kc, u16* __restrict__ vc)
{
  __shared__ u16 SM[24576];            // 49152 B: 3 ring bufs; epilogue Ct[128][136]
  const int K = 512;
  int bid0 = blockIdx.x;               // 768 linear
  int xcd = bid0 & 7, idx = bid0 >> 3; // idx 0..95
  int mblk = xcd*8 + idx/12;
  int nblk = idx % 12;
  int n0 = nblk*128, m0 = mblk*128;
  int t = threadIdx.x, wave = t>>6, lane = t&63;
  int wm = (wave>>1)*64, wn = (wave&1)*64;
  f32x4 acc[4][4] = {};
  int srow = wave*32 + (lane>>2);
  int scol = (lane&3)*8;
  const u16* gA = A + (size_t)(m0+srow)*K + scol;
  const u16* gB = W + (size_t)(n0+srow)*K + scol;
  int q8 = (lane>>4)*8, r16 = lane&15;
  auto STAGE = [&](u16* buf, int k0){
    u16* lA = buf + wave*1024;
    u16* lB = buf + 4096 + wave*1024;
    async_ld16(gA + k0,                lA);
    async_ld16(gA + k0 + 16*(size_t)K, lA + 512);
    async_ld16(gB + k0,                lB);
    async_ld16(gB + k0 + 16*(size_t)K, lB + 512);
  };
  u16 *cB = SM, *nB = SM + 8192, *tB = SM + 16384;
  STAGE(cB, 0);
  STAGE(nB, 32);
  for (int k0=0; k0<K; k0+=32){
    if (k0 + 32 < K) asm volatile("s_waitcnt vmcnt(4)" ::: "memory");
    else             asm volatile("s_waitcnt vmcnt(0)" ::: "memory");
    __builtin_amdgcn_s_barrier();
    if (k0 + 64 < K) STAGE(tB, k0 + 64);
    bf16x8 af[4], bfr[4];
    #pragma unroll
    for (int i=0;i<4;i++) af[i]  = *(const bf16x8*)&cB[(wm + i*16 + r16)*32 + q8];
    #pragma unroll
    for (int j=0;j<4;j++) bfr[j] = *(const bf16x8*)&cB[4096 + (wn + j*16 + r16)*32 + q8];
    #pragma unroll
    for (int i=0;i<4;i++)
      #pragma unroll
      for (int j=0;j<4;j++)
        acc[i][j] = __builtin_amdgcn_mfma_f32_16x16x32_bf16(af[i], bfr[j], acc[i][j], 0,0,0);
    u16* tmp = cB; cB = nB; nB = tB; tB = tmp;
  }
  __syncthreads();                     // all K-loop LDS reads done; SM reusable
  // ---- epilogue v2 ----
  int g = lane>>4;
  #pragma unroll
  for (int j=0;j<4;j++){
    int col = wn + j*16 + r16;
    float bv = bias[n0 + col];
    #pragma unroll
    for (int i=0;i<4;i++){
      int rbase = wm + i*16 + g*4;
      #pragma unroll
      for (int r=0;r<4;r++)
        SM[(rbase+r)*136 + col] = f2bf(acc[i][j][r] + bv);
    }
  }
  __syncthreads();
  int sec = n0 >> 9;                   // 0=q, 1=k, 2=v (uniform per block)
  #pragma unroll
  for (int u=0;u<8;u++){
    int idx2 = t + 256*u;              // 2048 uint4 groups
    int rloc = idx2 >> 4;              // 0..127
    int colg = (idx2 & 15) * 8;        // 0..120
    int row = m0 + rloc;
    int nn = (n0 + colg) & 511;
    int h2 = nn>>6, e0 = nn&63;
    int bh2 = ((row>>12)<<3) | h2;
    int bid = (bh2<<6) | ((row>>6)&63);
    int l6 = row & 63;
    union { uint4 v; u16 s[8]; } dat;
    dat.v = *(const uint4*)&SM[rloc*136 + colg];
    size_t a = ((size_t)(bid*2 + (e0>>5)))*2048 + (size_t)l6*32 + (e0&31);
    if (sec == 0){
      float eqc = __expf(cb[((size_t)bh2<<12) | (row & 4095)])*0.125f;
      #pragma unroll
      for (int jj=0;jj<8;jj++) dat.s[jj] = f2bf(elu1(bf2f(dat.s[jj]))*eqc);
      *(uint4*)(qc + a) = dat.v;
    } else if (sec == 1){
      float ekc = __expf(-cb[((size_t)bh2<<12) | (row & 4095)]);
      #pragma unroll
      for (int jj=0;jj<8;jj++) dat.s[jj] = f2bf(elu1(bf2f(dat.s[jj]))*ekc);
      *(uint4*)(kc + a) = dat.v;
    } else {
      *(uint4*)(vc + a) = dat.v;
    }
  }
}

// XCD-aligned chunk id: hw block i -> the (bh,ch) whose producer K3 block ran on XCD i%8.
__device__ __forceinline__ int chunk_bid_remap(int i){
  int xcd = i & 7;
  int b = xcd >> 2, chhi = xcd & 3;
  int idx = i >> 3;                    // 0..127
  int h = idx >> 4, chlo = idx & 15;
  int ch = (chhi<<4) | chlo;
  return (((b<<3)|h)<<6) | ch;
}

// ---------------- K4: per-chunk S^T MFMA + k~ sums (from chunked k~/v) ----------------
__global__ __launch_bounds__(256) void chunk_sums_kernel(const u16* __restrict__ kc,
    const u16* __restrict__ vc, u16* __restrict__ Stc, float* __restrict__ ksc)
{
  int bid = chunk_bid_remap(blockIdx.x);
  __shared__ u16 Kc[4096], Vc[4096];
  __shared__ u16 Ktl[5120], Vtl[5120];     // [2][64][40] padded
  __shared__ float ksr[256];
  int t = threadIdx.x, w = t>>6, lane = t&63;
  {
    const u16* gk = kc + (size_t)bid*4096 + w*1024 + lane*8;
    const u16* gv = vc + (size_t)bid*4096 + w*1024 + lane*8;
    async_ld16(gk,       Kc + w*1024);
    async_ld16(gk + 512, Kc + w*1024 + 512);
    async_ld16(gv,       Vc + w*1024);
    async_ld16(gv + 512, Vc + w*1024 + 512);
  }
  __syncthreads();
  int e = t & 63, jq = t >> 6;
  {
    u16 kv[16] __attribute__((aligned(16)));
    u16 vv[16] __attribute__((aligned(16)));
    float ksum = 0.f;
    #pragma unroll
    for (int jj=0;jj<16;jj++){
      int j = jq*16+jj;
      kv[jj] = Kc[(e>>5)*2048 + j*32 + (e&31)];
      ksum += bf2f(kv[jj]);
      vv[jj] = Vc[(e>>5)*2048 + j*32 + (e&31)];
    }
    int kh2 = jq>>1, jl = (jq&1)*16;
    u16* kt = &Ktl[(kh2*64 + e)*40 + jl];
    u16* vt = &Vtl[(kh2*64 + e)*40 + jl];
    *(uint4*)kt     = *(const uint4*)&kv[0];
    *(uint4*)(kt+8) = *(const uint4*)&kv[8];
    *(uint4*)vt     = *(const uint4*)&vv[0];
    *(uint4*)(vt+8) = *(const uint4*)&vv[8];
    ksr[t] = ksum;
  }
  __syncthreads();
  int r16 = lane & 15, q8 = (lane>>4)*8;
  bf16x8 av[2];
  #pragma unroll
  for (int kh=0;kh<2;kh++)
    av[kh] = *(const bf16x8*)&Vtl[(kh*64 + w*16 + r16)*40 + q8];
  f32x4 acc[4] = {};
  #pragma unroll
  for (int et=0;et<4;et++)
    #pragma unroll
    for (int kh=0;kh<2;kh++){
      bf16x8 bv = *(const bf16x8*)&Ktl[(kh*64 + et*16 + r16)*40 + q8];
      acc[et] = __builtin_amdgcn_mfma_f32_16x16x32_bf16(av[kh], bv, acc[et], 0,0,0);
    }
  #pragma unroll
  for (int et=0;et<4;et++){
    int eh = et>>1, el = (et&1)*16 + r16;
    #pragma unroll
    for (int r=0;r<4;r++){
      int f = w*16 + (lane>>4)*4 + r;
      Stc[((size_t)bid*2 + eh)*2048 + f*32 + el] = f2bf(acc[et][r]);
    }
  }
  if (t < 64) ksc[bid*64 + t] = ksr[t] + ksr[64+t] + ksr[128+t] + ksr[192+t];
}

// ---------------- K5: exclusive prefix over chunks ----------------
__global__ __launch_bounds__(256) void chunk_prefix_kernel(u16* __restrict__ Stc,
    float* __restrict__ ksc)
{
  int blk = blockIdx.x, t = threadIdx.x;
  if (blk < 128){
    int gid = blk*256 + t;                 // 32768 threads
    int bh = gid >> 11, e2 = gid & 2047;
    u32* p = (u32*)Stc + (size_t)bh*131072 + e2;
    float r0 = 0.f, r1 = 0.f;
    #pragma unroll 16
    for (int ch=0; ch<NCH; ch++){
      u32 v = p[ch*2048];
      float lo = bf2f((u16)(v & 0xffffu));
      float hi = bf2f((u16)(v >> 16));
      p[ch*2048] = (u32)f2bf(r0) | ((u32)f2bf(r1) << 16);
      r0 += lo; r1 += hi;
    }
  } else {
    int gid2 = (blk-128)*256 + t;          // 1024 threads = BH*64
    int bh2 = gid2 >> 6, e = gid2 & 63;
    float* kp = ksc + bh2*4096 + e;
    float kr = 0.f;
    #pragma unroll 8
    for (int ch=0; ch<NCH; ch++){
      float v = kp[ch*64]; kp[ch*64] = kr; kr += v;
    }
  }
}

// ---------------- K6: chunk output (Q & S^T fragments direct-from-global) ----------------
__global__ __launch_bounds__(256) void chunk_out_kernel(const u16* __restrict__ qc,
    const u16* __restrict__ kc, const u16* __restrict__ vc,
    const u16* __restrict__ Stc, const float* __restrict__ ksc,
    u16* __restrict__ attn)
{
  int bid = chunk_bid_remap(blockIdx.x);
  int bh = bid >> 6, ch = bid & 63;
  int b = bh >> 3, h = bh & 7;
  __shared__ u16 Kb_l[4096];
  __shared__ u16 Vc_l[4096];
  __shared__ u16 Vt[5120];       // [2][64][40] padded
  __shared__ u16 Ab[4096];       // [jh][l][32]
  __shared__ float R2[320];      // [0..255] den4, [256..319] den
  int t = threadIdx.x, w = t>>6, lane = t&63;
  size_t mbase = (size_t)b*L_ + ch*64;
  {
    const u16* gk = kc  + (size_t)bid*4096 + w*1024 + lane*8;
    const u16* gv = vc  + (size_t)bid*4096 + w*1024 + lane*8;
    async_ld16(gk,       Kb_l + w*1024);
    async_ld16(gk + 512, Kb_l + w*1024 + 512);
    async_ld16(gv,       Vc_l + w*1024);
    async_ld16(gv + 512, Vc_l + w*1024 + 512);
  }
  int r16 = lane & 15, q8 = (lane>>4)*8;
  // Q, S^T fragments + kp direct from global, issued before the barrier
  const u16* qg = qc  + (size_t)bid*4096;
  const u16* sg = Stc + (size_t)bid*4096;
  bf16x8 aq[2], sfr[2][4];
  #pragma unroll
  for (int eh=0;eh<2;eh++){
    aq[eh] = *(const bf16x8*)(qg + eh*2048 + (w*16 + r16)*32 + q8);
    #pragma unroll
    for (int ft=0;ft<4;ft++)
      sfr[eh][ft] = *(const bf16x8*)(sg + (eh*64 + ft*16 + r16)*32 + q8);
  }
  int l4 = t>>2, q4 = t&3;
  int ehd = q4>>1, el0 = (q4&1)*16;
  bf16x8 x1 = *(const bf16x8*)(qg + ehd*2048 + l4*32 + el0);
  bf16x8 x2 = *(const bf16x8*)(qg + ehd*2048 + l4*32 + el0 + 8);
  union { float4 v[4]; float f[16]; } kp;
  #pragma unroll
  for (int qq=0;qq<4;qq++)
    kp.v[qq] = *(const float4*)(ksc + bid*64 + q4*16 + qq*4);
  __syncthreads();   // B1: staging drained
  // V transpose: Vc_l (chunk row layout) -> Vt (padded 40)
  {
    int e = t & 63, jq = t >> 6;
    u16 vv[16] __attribute__((aligned(16)));
    #pragma unroll
    for (int jj=0;jj<16;jj++)
      vv[jj] = Vc_l[(e>>5)*2048 + (jq*16+jj)*32 + (e&31)];
    int jh = jq>>1, jl = (jq&1)*16;
    u16* vt = &Vt[(jh*64 + e)*40 + jl];
    *(uint4*)vt     = *(const uint4*)&vv[0];
    *(uint4*)(vt+8) = *(const uint4*)&vv[8];
  }
  // matmul1: A = Q~ K~^T  (strip l = w*16..w*16+15)
  f32x4 accA[4] = {};
  #pragma unroll
  for (int jt=0;jt<4;jt++)
    #pragma unroll
    for (int eh=0;eh<2;eh++){
      bf16x8 bv = *(const bf16x8*)&Kb_l[(eh*64 + jt*16 + r16)*32 + q8];
      accA[jt] = __builtin_amdgcn_mfma_f32_16x16x32_bf16(aq[eh], bv, accA[jt], 0,0,0);
    }
  // den: q~ . kp part
  float dkp = 0.f;
  #pragma unroll
  for (int i=0;i<8;i++)
    dkp += bf2f((u16)x1[i])*kp.f[i] + bf2f((u16)x2[i])*kp.f[8+i];
  // mask + write A to LDS (bf16, split layout)
  #pragma unroll
  for (int jt=0;jt<4;jt++)
    #pragma unroll
    for (int r=0;r<4;r++){
      int lr = w*16 + ((lane>>4)<<2) + r;
      int j  = jt*16 + r16;
      Ab[((jt>>1)*64 + lr)*32 + (jt&1)*16 + r16] = (j <= lr) ? f2bf(accA[jt][r]) : (u16)0;
    }
  __syncthreads();   // B2: Ab + Vt visible
  // den: masked row-sum of A
  float dA = 0.f;
  {
    int jh2 = q4>>1, jl0 = (q4&1)*16;
    bf16x8 y1 = *(const bf16x8*)&Ab[(jh2*64 + l4)*32 + jl0];
    bf16x8 y2 = *(const bf16x8*)&Ab[(jh2*64 + l4)*32 + jl0 + 8];
    #pragma unroll
    for (int i=0;i<8;i++) dA += bf2f((u16)y1[i]) + bf2f((u16)y2[i]);
  }
  R2[t] = dkp + dA;
  __syncthreads();   // B3
  if (t < 64) R2[256+t] = R2[t*4] + R2[t*4+1] + R2[t*4+2] + R2[t*4+3] + 1e-6f;
  // matmul2: num = A V + Q~ S^T
  bf16x8 aA[2];
  #pragma unroll
  for (int jh=0;jh<2;jh++)
    aA[jh] = *(const bf16x8*)&Ab[(jh*64 + w*16 + r16)*32 + q8];
  f32x4 acc[4] = {};
  #pragma unroll
  for (int ft=0;ft<4;ft++){
    #pragma unroll
    for (int jh=0;jh<2;jh++){
      bf16x8 bv = *(const bf16x8*)&Vt[(jh*64 + ft*16 + r16)*40 + q8];
      acc[ft] = __builtin_amdgcn_mfma_f32_16x16x32_bf16(aA[jh], bv, acc[ft], 0,0,0);
    }
    #pragma unroll
    for (int eh=0;eh<2;eh++)
      acc[ft] = __builtin_amdgcn_mfma_f32_16x16x32_bf16(aq[eh], sfr[eh][ft], acc[ft], 0,0,0);
  }
  __syncthreads();   // B4: den ready
  float inv[4];
  #pragma unroll
  for (int r=0;r<4;r++) inv[r] = 1.f / R2[256 + w*16 + ((lane>>4)<<2) + r];
  #pragma unroll
  for (int ft=0;ft<4;ft++)
    #pragma unroll
    for (int r=0;r<4;r++){
      int lr = w*16 + ((lane>>4)<<2) + r;
      attn[(mbase + lr)*D_ + h*64 + ft*16 + r16] = f2bf(acc[ft][r]*inv[r]);
    }
}

// ---------------- K7: out-proj GEMM + RMSNorm ----------------
__global__ __launch_bounds__(256) void gemm_rms_kernel(const u16* __restrict__ A,
    const u16* __restrict__ W, const float* __restrict__ bias,
    const float* __restrict__ gnorm, float* __restrict__ out)
{
  __shared__ u16 As[2][1024];
  __shared__ u16 Bs[2][16384];
  __shared__ float ssq_l[4][32];
  __shared__ float rinv_l[32];
  int m0 = blockIdx.x*32;
  int t = threadIdx.x, wave = t>>6, lane = t&63;
  int wn = wave*128;
  int r16 = lane&15, q8 = (lane>>4)*8;
  f32x4 acc[2][8] = {};
  int scol = (t&3)*8;
  const u16* gB = W + (size_t)(t>>2)*512 + scol;
  const u16* gA = A + (size_t)(m0 + (t>>2))*512 + scol;
  {
    if (wave < 2) async_ld16(gA, As[0] + wave*512);
    #pragma unroll
    for (int it=0; it<8; it++)
      async_ld16(gB + it*32768, Bs[0] + wave*512 + it*2048);
  }
  int cur = 0;
  for (int k0=0; k0<512; k0+=32){
    asm volatile("s_waitcnt vmcnt(0)" ::: "memory");
    __builtin_amdgcn_s_barrier();
    if (k0 < 480){
      if (wave < 2) async_ld16(gA + k0+32, As[cur^1] + wave*512);
      #pragma unroll
      for (int it=0; it<8; it++)
        async_ld16(gB + k0+32 + it*32768, Bs[cur^1] + wave*512 + it*2048);
    }
    bf16x8 af0 = *(const bf16x8*)&As[cur][r16*32 + q8];
    bf16x8 af1 = *(const bf16x8*)&As[cur][(16 + r16)*32 + q8];
    #pragma unroll
    for (int j=0;j<8;j++){
      bf16x8 bv = *(const bf16x8*)&Bs[cur][(wn + j*16 + r16)*32 + q8];
      acc[0][j] = __builtin_amdgcn_mfma_f32_16x16x32_bf16(af0, bv, acc[0][j], 0,0,0);
      acc[1][j] = __builtin_amdgcn_mfma_f32_16x16x32_bf16(af1, bv, acc[1][j], 0,0,0);
    }
    cur ^= 1;
  }
  int g = lane>>4;
  float bv8[8], gv8[8];
  #pragma unroll
  for (int j=0;j<8;j++){ int col = wn + j*16 + r16; bv8[j] = bias[col]; gv8[j] = gnorm[col]; }
  float ssq[2][4] = {};
  #pragma unroll
  for (int i=0;i<2;i++)
    #pragma unroll
    for (int j=0;j<8;j++)
      #pragma unroll
      for (int r=0;r<4;r++){
        float v = acc[i][j][r] + bv8[j];
        acc[i][j][r] = v;
        ssq[i][r] += v*v;
      }
  #pragma unroll
  for (int off=1; off<16; off<<=1)
    #pragma unroll
    for (int i=0;i<2;i++)
      #pragma unroll
      for (int r=0;r<4;r++)
        ssq[i][r] += __shfl_xor(ssq[i][r], off);
  if (r16 == 0){
    #pragma unroll
    for (int i=0;i<2;i++)
      #pragma unroll
      for (int r=0;r<4;r++)
        ssq_l[wave][i*16 + g*4 + r] = ssq[i][r];
  }
  __syncthreads();
  if (t < 32)
    rinv_l[t] = rsqrtf((ssq_l[0][t]+ssq_l[1][t]+ssq_l[2][t]+ssq_l[3][t])*(1.f/512.f) + 1e-8f);
  __syncthreads();
  #pragma unroll
  for (int i=0;i<2;i++)
    #pragma unroll
    for (int r=0;r<4;r++){
      int row = m0 + i*16 + g*4 + r;
      float ri = rinv_l[i*16 + g*4 + r];
      #pragma unroll
      for (int j=0;j<8;j++)
        out[(size_t)row*512 + wn + j*16 + r16] = acc[i][j][r]*ri*gv8[j];
    }
}

extern "C" void kernel_launch(void* const* d_in, const int* in_sizes, int n_in,
                              void* d_out, int out_size, void* d_ws, size_t ws_size,
                              hipStream_t stream)
{
  const float* x     = (const float*)d_in[0];
  const float* w_qkv = (const float*)d_in[1];
  const float* b_qkv = (const float*)d_in[2];
  const float* w_out = (const float*)d_in[3];
  const float* b_out = (const float*)d_in[4];
  const float* w_dec = (const float*)d_in[5];
  const float* b_dec = (const float*)d_in[6];
  const float* gnorm = (const float*)d_in[7];
  float* out = (float*)d_out;

  char* ws = (char*)d_ws;
  u16*   qc   = (u16*)(ws);                    //  8,388,608  chunked q~
  u16*   kc   = (u16*)(ws + 8388608);          //  8,388,608  chunked k~
  u16*   vc   = (u16*)(ws + 16777216);         //  8,388,608  chunked raw v
  u16*   Stc  = (u16*)(ws + 25165824);         //  8,388,608  chunked [bid][eh][f][32]
  float* ksc  = (float*)(ws + 33554432);       //    262,144
  float* ll   = (float*)(ws + 33816576);       //    262,144
  float* cb   = (float*)(ws + 34078720);       //    262,144
  u16*   xb   = (u16*)(ws + 34340864);         //  8,388,608  (attn reuses)
  u16*   qwb  = (u16*)(ws + 42729472);         //  1,572,864
  u16*   owb  = (u16*)(ws + 44302336);         //    524,288  total 44,826,624
  u16*   attn = xb;

  decay_conv_kernel<<<dim3(3072), dim3(256), 0, stream>>>(x, w_dec, b_dec, w_qkv, w_out,
                                                          ll, xb, qwb, owb);
  scan_kernel<<<dim3(BH), dim3(256), 0, stream>>>(ll, cb);
  gemm_qkv_fused<<<dim3(768), dim3(256), 0, stream>>>(xb, qwb, b_qkv, cb, qc, kc, vc);
  chunk_sums_kernel<<<dim3(BH*NCH), dim3(256), 0, stream>>>(kc, vc, Stc, ksc);
  chunk_prefix_kernel<<<dim3(132), dim3(256), 0, stream>>>(Stc, ksc);
  chunk_out_kernel<<<dim3(BH*NCH), dim3(256), 0, stream>>>(qc, kc, vc, Stc, ksc, attn);
  gemm_rms_kernel<<<dim3(M_/32), dim3(256), 0, stream>>>(attn, owb, b_out, gnorm, out);
}